// Round 5
// baseline (2512.550 us; speedup 1.0000x reference)
//
#include <hip/hip_runtime.h>

// GPT-2 forward. Round 5: counted-vmcnt pipelined GEMMs (T3/T4): layer GEMMs
// 3-buffer depth-2 prefetch, logits 256²/8-wave 2-buffer; raw s_barrier +
// asm vmcnt(N) (never drain to 0 in-loop); setprio around MFMA (T5).

#define LL 12
#define DM 1024
#define NH 16
#define DHD 64
#define NV 50257
#define NVP 50432  // 197*256
#define SQ 512
#define NB 4
#define DF 4096
#define MR (NB * SQ)

typedef short bf16x8 __attribute__((ext_vector_type(8)));
typedef float f32x4 __attribute__((ext_vector_type(4)));
typedef unsigned short u16;

__device__ __forceinline__ u16 f2b(float f) {  // f32 -> bf16 RNE
  unsigned u = __float_as_uint(f);
  u += 0x7fff + ((u >> 16) & 1);
  return (u16)(u >> 16);
}

__device__ __forceinline__ void gload16(const u16* g, u16* l) {
  __builtin_amdgcn_global_load_lds(
      (const __attribute__((address_space(1))) unsigned*)g,
      (__attribute__((address_space(3))) unsigned*)l, 16, 0, 0);
}

template <int N>
__device__ __forceinline__ void waitvm() {
  if constexpr (N == 0) asm volatile("s_waitcnt vmcnt(0)" ::: "memory");
  else if constexpr (N == 4) asm volatile("s_waitcnt vmcnt(4)" ::: "memory");
  else if constexpr (N == 6) asm volatile("s_waitcnt vmcnt(6)" ::: "memory");
  else if constexpr (N == 8) asm volatile("s_waitcnt vmcnt(8)" ::: "memory");
  else if constexpr (N == 12) asm volatile("s_waitcnt vmcnt(12)" ::: "memory");
  else asm volatile("s_waitcnt vmcnt(16)" ::: "memory");
}

__device__ __forceinline__ void barrier_sb() {
  __builtin_amdgcn_s_barrier();
  __builtin_amdgcn_sched_barrier(0);
}

// ---------------- GEMM: C[M,N] = A[M,K](bf16) @ B[N,K](bf16)^T --------------
// MODE 1: Cf32 += acc + bias   MODE 2: bf16 C = gelu(acc+bias)
// MODE 6: logits f32, n<NV     MODE 7: QKV fused (route n>>10), V transposed
// Counted-vmcnt pipeline, NBUF LDS buffers (depth NBUF-1 prefetch),
// 2 raw barriers/K-step, loads in flight across barriers.
// LDS linear [rows][64]; global source pre-swizzled; XOR on read (rule #21).
template <int MODE, int TBM, int TBN, int MTLOG, int NT, int NBUF>
__global__ __launch_bounds__(NT, 2) void gemm_k(
    const u16* __restrict__ A, const u16* __restrict__ B, void* __restrict__ Cp,
    void* __restrict__ Cp2, void* __restrict__ Cp3,
    const float* __restrict__ bias, int N, int K, int lda, int ldb, int ldc) {
  constexpr int NW = NT / 64;          // waves per block
  constexpr int WN = (NW == 8) ? 4 : 2, WM = 2;
  constexpr int FM = TBM / (WM * 16), FN = TBN / (WN * 16);
  constexpr int LPT = (TBM + TBN) / (8 * NW);  // 1KB chunks per thread
  constexpr int NCA = TBM / 8;                 // A chunk count

  int id = blockIdx.x;
  int q8 = gridDim.x >> 3;
  int swz = (id & 7) * q8 + (id >> 3);
  int mt = swz & ((1 << MTLOG) - 1), nt = swz >> MTLOG;
  int m0 = mt * TBM, n0 = nt * TBN;

  __shared__ u16 As[NBUF][TBM * 64];
  __shared__ u16 Bs[NBUF][TBN * 64];

  int t = threadIdx.x, lane = t & 63, wave = t >> 6;
  int wm = wave / WN, wn = wave % WN;
  int lr = lane & 15, g = lane >> 4;
  int srow = lane >> 3;
  int sxcol = ((lane & 7) ^ (lane >> 3)) << 3;  // inverse-swizzled global col
  int rsw = (lr & 7) << 3;                      // read-side XOR (u16 units)

  f32x4 acc[FM][FN];
#pragma unroll
  for (int i = 0; i < FM; ++i)
#pragma unroll
    for (int j = 0; j < FN; ++j) acc[i][j] = (f32x4){0.f, 0.f, 0.f, 0.f};

  auto stage = [&](int buf, int ktile) {
    int k0 = ktile * 64;
#pragma unroll
    for (int v = 0; v < LPT; ++v) {
      int c = v * NW + wave;
      if (c < NCA) {
        gload16(A + (size_t)(m0 + c * 8 + srow) * lda + k0 + sxcol,
                &As[buf][c * 512]);
      } else {
        int cb = c - NCA;
        gload16(B + (size_t)(n0 + cb * 8 + srow) * ldb + k0 + sxcol,
                &Bs[buf][cb * 512]);
      }
    }
  };

  auto compute = [&](int buf) {
#pragma unroll
    for (int ks = 0; ks < 2; ++ks) {
      int co = (ks * 32 + g * 8) ^ rsw;
      bf16x8 af[FM];
#pragma unroll
      for (int i = 0; i < FM; ++i)
        af[i] =
            *(const bf16x8*)&As[buf][(wm * (TBM / WM) + i * 16 + lr) * 64 + co];
#pragma unroll
      for (int jh = 0; jh < FN; jh += 2) {
        bf16x8 b0 =
            *(const bf16x8*)&Bs[buf][(wn * (TBN / WN) + jh * 16 + lr) * 64 + co];
        bf16x8 b1 = *(const bf16x8*)&Bs[buf][(wn * (TBN / WN) + (jh + 1) * 16 + lr) *
                                                 64 + co];
        __builtin_amdgcn_s_setprio(1);
#pragma unroll
        for (int i = 0; i < FM; ++i)
          acc[i][jh] =
              __builtin_amdgcn_mfma_f32_16x16x32_bf16(af[i], b0, acc[i][jh], 0, 0, 0);
#pragma unroll
        for (int i = 0; i < FM; ++i)
          acc[i][jh + 1] = __builtin_amdgcn_mfma_f32_16x16x32_bf16(
              af[i], b1, acc[i][jh + 1], 0, 0, 0);
        __builtin_amdgcn_s_setprio(0);
      }
    }
  };

  int nk = K >> 6;
#pragma unroll
  for (int p = 0; p < NBUF - 1; ++p) stage(p, p);  // prologue: depth fill
  int cbuf = 0, sbuf = NBUF - 1;
  int kt = 0;
#pragma unroll 1
  for (; kt < nk - (NBUF - 1); ++kt) {
    stage(sbuf, kt + NBUF - 1);   // prefetch; target buf read 2 barriers ago
    waitvm<(NBUF - 1) * LPT>();   // oldest tile (kt) landed; rest in flight
    barrier_sb();
    compute(cbuf);
    barrier_sb();                 // all waves done reading cbuf
    cbuf = cbuf + 1 == NBUF ? 0 : cbuf + 1;
    sbuf = sbuf + 1 == NBUF ? 0 : sbuf + 1;
  }
  if constexpr (NBUF == 3) {      // tail: 2 tiles left in flight
    waitvm<LPT>();
    barrier_sb();
    compute(cbuf);
    barrier_sb();
    cbuf = cbuf + 1 == NBUF ? 0 : cbuf + 1;
  }
  waitvm<0>();                    // last tile
  barrier_sb();
  compute(cbuf);

  // epilogue (C/D frag: col = lane&15, row = (lane>>4)*4 + r)
  int rb = g * 4;
#pragma unroll
  for (int i = 0; i < FM; ++i) {
#pragma unroll
    for (int j = 0; j < FN; ++j) {
      int m = m0 + wm * (TBM / WM) + i * 16 + rb;
      int n = n0 + wn * (TBN / WN) + j * 16 + lr;
      f32x4 a = acc[i][j];
      if constexpr (MODE == 1) {
        float* C = (float*)Cp;
        float bv = bias[n];
#pragma unroll
        for (int r = 0; r < 4; ++r) {
          size_t ix = (size_t)(m + r) * ldc + n;
          C[ix] += a[r] + bv;
        }
      } else if constexpr (MODE == 2) {
        u16* C = (u16*)Cp;
        float bv = bias[n];
#pragma unroll
        for (int r = 0; r < 4; ++r) {
          float u2 = a[r] + bv;
          float gl =
              0.5f * u2 *
              (1.f + tanhf(0.7978845608f * (u2 + 0.044715f * u2 * u2 * u2)));
          C[(size_t)(m + r) * ldc + n] = f2b(gl);
        }
      } else if constexpr (MODE == 6) {
        if (n < NV) {
          float* C = (float*)Cp;
#pragma unroll
          for (int r = 0; r < 4; ++r) C[(size_t)(m + r) * ldc + n] = a[r];
        }
      } else if constexpr (MODE == 7) {
        int sel = n >> 10, nn = n & 1023;
        if (sel < 2) {
          u16* C = sel == 0 ? (u16*)Cp : (u16*)Cp2;
#pragma unroll
          for (int r = 0; r < 4; ++r) C[(size_t)(m + r) * ldc + nn] = f2b(a[r]);
        } else {  // V transposed: vt[b][d][s]
          u16* C = (u16*)Cp3;
          int bb = m >> 9, s2 = m & (SQ - 1);
          ushort4 w4;
          w4.x = f2b(a[0]); w4.y = f2b(a[1]);
          w4.z = f2b(a[2]); w4.w = f2b(a[3]);
          *(ushort4*)&C[((size_t)bb * DM + nn) * SQ + s2] = w4;
        }
      }
    }
  }
}

// -------- flash attention: one block = (qt 64 q-rows, b,h); 4 waves ---------
__global__ __launch_bounds__(256) void fattn_k(const u16* __restrict__ qb,
                                               const u16* __restrict__ kb,
                                               const u16* __restrict__ vt,
                                               u16* __restrict__ cx) {
  int id = blockIdx.x;
  int qt = id >> 6, bh = id & 63;
  int b = bh >> 4, hh = bh & 15;
  int t = threadIdx.x, lane = t & 63, w = t >> 6;
  int lr = lane & 15, g = lane >> 4;

  __shared__ u16 Kt[64 * 72];
  __shared__ u16 Vt[64 * 72];
  __shared__ u16 Pl[4 * 16 * 72];

  int qw = qt * 64 + w * 16;

  bf16x8 aQ[2];
#pragma unroll
  for (int f = 0; f < 2; ++f)
    aQ[f] = *(const bf16x8*)&qb[(size_t)(b * SQ + qw + lr) * DM + hh * DHD +
                                f * 32 + g * 8];

  f32x4 o[4];
#pragma unroll
  for (int j = 0; j < 4; ++j) o[j] = (f32x4){0.f, 0.f, 0.f, 0.f};
  f32x4 m4 = (f32x4){-3e38f, -3e38f, -3e38f, -3e38f};
  f32x4 l4 = (f32x4){0.f, 0.f, 0.f, 0.f};
  u16* Pw = &Pl[w * 16 * 72];

  for (int kt = 0; kt <= qt; ++kt) {
    int k0 = kt * 64;
#pragma unroll
    for (int it = 0; it < 2; ++it) {
      int c = t + it * 256;
      int row = c >> 3, ch = c & 7;
      int4 kv = *(const int4*)&kb[(size_t)(b * SQ + k0 + row) * DM + hh * DHD +
                                  ch * 8];
      int4 vv = *(const int4*)&vt[(size_t)(b * DM + hh * DHD + row) * SQ + k0 +
                                  ch * 8];
      *(int4*)&Kt[row * 72 + ch * 8] = kv;
      *(int4*)&Vt[row * 72 + ch * 8] = vv;
    }
    __syncthreads();

    f32x4 s[4];
#pragma unroll
    for (int j = 0; j < 4; ++j) s[j] = (f32x4){0.f, 0.f, 0.f, 0.f};
#pragma unroll
    for (int j = 0; j < 4; ++j)
#pragma unroll
      for (int f = 0; f < 2; ++f) {
        bf16x8 bk = *(const bf16x8*)&Kt[(j * 16 + lr) * 72 + f * 32 + g * 8];
        s[j] =
            __builtin_amdgcn_mfma_f32_16x16x32_bf16(aQ[f], bk, s[j], 0, 0, 0);
      }
#pragma unroll
    for (int j = 0; j < 4; ++j) {
      int kcol = k0 + j * 16 + lr;
#pragma unroll
      for (int r = 0; r < 4; ++r) {
        float sv = s[j][r] * 0.125f;
        if (kt == qt && kcol > qw + g * 4 + r) sv = -1e30f;
        s[j][r] = sv;
      }
    }
    f32x4 fr;
#pragma unroll
    for (int r = 0; r < 4; ++r) {
      float v = fmaxf(fmaxf(s[0][r], s[1][r]), fmaxf(s[2][r], s[3][r]));
#pragma unroll
      for (int d = 1; d < 16; d <<= 1) v = fmaxf(v, __shfl_xor(v, d));
      float mn = fmaxf(m4[r], v);
      fr[r] = __expf(m4[r] - mn);
      m4[r] = mn;
    }
#pragma unroll
    for (int j = 0; j < 4; ++j)
#pragma unroll
      for (int r = 0; r < 4; ++r) o[j][r] *= fr[r];
    f32x4 ps = (f32x4){0.f, 0.f, 0.f, 0.f};
#pragma unroll
    for (int j = 0; j < 4; ++j)
#pragma unroll
      for (int r = 0; r < 4; ++r) {
        float p = __expf(s[j][r] - m4[r]);
        s[j][r] = p;
        ps[r] += p;
      }
#pragma unroll
    for (int r = 0; r < 4; ++r) {
      float v = ps[r];
#pragma unroll
      for (int d = 1; d < 16; d <<= 1) v += __shfl_xor(v, d);
      l4[r] = l4[r] * fr[r] + v;
    }
#pragma unroll
    for (int j = 0; j < 4; ++j)
#pragma unroll
      for (int r = 0; r < 4; ++r)
        Pw[(g * 4 + r) * 72 + j * 16 + lr] = f2b(s[j][r]);
#pragma unroll
    for (int f = 0; f < 2; ++f) {
      bf16x8 ap = *(const bf16x8*)&Pw[lr * 72 + f * 32 + g * 8];
#pragma unroll
      for (int j = 0; j < 4; ++j) {
        bf16x8 bv = *(const bf16x8*)&Vt[(j * 16 + lr) * 72 + f * 32 + g * 8];
        o[j] = __builtin_amdgcn_mfma_f32_16x16x32_bf16(ap, bv, o[j], 0, 0, 0);
      }
    }
    __syncthreads();
  }

#pragma unroll
  for (int r = 0; r < 4; ++r) {
    float inv = 1.f / l4[r];
#pragma unroll
    for (int j = 0; j < 4; ++j)
      cx[(size_t)(b * SQ + qw + g * 4 + r) * DM + hh * DHD + j * 16 + lr] =
          f2b(o[j][r] * inv);
  }
}

// ---- merged: weight transpose (blocks 0..3071) + ln1 (blocks 3072..5119) ---
__global__ __launch_bounds__(256) void transpln_k(
    const float* __restrict__ Wq, const float* __restrict__ Wk,
    const float* __restrict__ Wv, const float* __restrict__ Wo,
    const float* __restrict__ W1, const float* __restrict__ W2,
    u16* __restrict__ wb, const float* __restrict__ x,
    const float* __restrict__ sc, const float* __restrict__ sh,
    u16* __restrict__ o) {
  __shared__ u16 tl[64][72];
  __shared__ float red[8];
  int t = threadIdx.x;
  if (blockIdx.x < 3072) {
    int id = blockIdx.x;
    const float* src;
    u16* dst;
    int K, N, ktile, ntile;
    if (id < 1024) {
      int mat = id >> 8, rem = id & 255;
      ntile = rem & 15; ktile = rem >> 4;
      src = mat == 0 ? Wq : mat == 1 ? Wk : mat == 2 ? Wv : Wo;
      dst = wb + (size_t)mat * DM * DM;
      K = DM; N = DM;
    } else if (id < 2048) {
      int rem = id - 1024;
      ntile = rem & 63; ktile = rem >> 6;
      src = W1; dst = wb + (size_t)4 * DM * DM;
      K = DM; N = DF;
    } else {
      int rem = id - 2048;
      ntile = rem & 15; ktile = rem >> 4;
      src = W2; dst = wb + (size_t)4 * DM * DM + (size_t)DM * DF;
      K = DF; N = DM;
    }
    int n0 = ntile * 64, k0 = ktile * 64;
    int tn = (t & 15) * 4, tk = t >> 4;
#pragma unroll
    for (int it = 0; it < 4; ++it) {
      int k = tk + it * 16;
      float4 v = *(const float4*)(src + (size_t)(k0 + k) * N + n0 + tn);
      tl[tn + 0][k] = f2b(v.x);
      tl[tn + 1][k] = f2b(v.y);
      tl[tn + 2][k] = f2b(v.z);
      tl[tn + 3][k] = f2b(v.w);
    }
    __syncthreads();
    int wn = t >> 3, wk = (t & 7) * 8;
#pragma unroll
    for (int it = 0; it < 2; ++it) {
      int n = wn + it * 32;
      int4 v = *(const int4*)&tl[n][wk];
      *(int4*)(dst + (size_t)(n0 + n) * K + k0 + wk) = v;
    }
  } else {
    int row = blockIdx.x - 3072;
    const float* xr = x + (size_t)row * DM;
    float4 v = *(const float4*)(xr + t * 4);
    float s = v.x + v.y + v.z + v.w;
#pragma unroll
    for (int d = 32; d; d >>= 1) s += __shfl_xor(s, d);
    if ((t & 63) == 0) red[t >> 6] = s;
    __syncthreads();
    float mean = (red[0] + red[1] + red[2] + red[3]) * (1.f / DM);
    float dx = v.x - mean, dy = v.y - mean, dz = v.z - mean, dw = v.w - mean;
    float s2 = dx * dx + dy * dy + dz * dz + dw * dw;
#pragma unroll
    for (int d = 32; d; d >>= 1) s2 += __shfl_xor(s2, d);
    if ((t & 63) == 0) red[4 + (t >> 6)] = s2;
    __syncthreads();
    float var = (red[4] + red[5] + red[6] + red[7]) * (1.f / DM);
    float rstd = 1.f / sqrtf(var + 1e-6f);
    float4 gg = *(const float4*)(sc + t * 4);
    float4 b = *(const float4*)(sh + t * 4);
    ushort4 w4;
    w4.x = f2b(gg.x * (dx * rstd) + b.x);
    w4.y = f2b(gg.y * (dy * rstd) + b.y);
    w4.z = f2b(gg.z * (dz * rstd) + b.z);
    w4.w = f2b(gg.w * (dw * rstd) + b.w);
    *(ushort4*)(o + (size_t)row * DM + t * 4) = w4;
  }
}

__global__ __launch_bounds__(256) void ln_k(const float* __restrict__ x,
                                            const float* __restrict__ sc,
                                            const float* __restrict__ sh,
                                            u16* __restrict__ o) {
  int row = blockIdx.x, t = threadIdx.x;
  const float* xr = x + (size_t)row * DM;
  float4 v = *(const float4*)(xr + t * 4);
  float s = v.x + v.y + v.z + v.w;
#pragma unroll
  for (int d = 32; d; d >>= 1) s += __shfl_xor(s, d);
  __shared__ float red[8];
  if ((t & 63) == 0) red[t >> 6] = s;
  __syncthreads();
  float mean = (red[0] + red[1] + red[2] + red[3]) * (1.f / DM);
  float dx = v.x - mean, dy = v.y - mean, dz = v.z - mean, dw = v.w - mean;
  float s2 = dx * dx + dy * dy + dz * dz + dw * dw;
#pragma unroll
  for (int d = 32; d; d >>= 1) s2 += __shfl_xor(s2, d);
  if ((t & 63) == 0) red[4 + (t >> 6)] = s2;
  __syncthreads();
  float var = (red[4] + red[5] + red[6] + red[7]) * (1.f / DM);
  float rstd = 1.f / sqrtf(var + 1e-6f);
  float4 g = *(const float4*)(sc + t * 4);
  float4 b = *(const float4*)(sh + t * 4);
  ushort4 w4;
  w4.x = f2b(g.x * (dx * rstd) + b.x);
  w4.y = f2b(g.y * (dy * rstd) + b.y);
  w4.z = f2b(g.z * (dz * rstd) + b.z);
  w4.w = f2b(g.w * (dw * rstd) + b.w);
  *(ushort4*)(o + (size_t)row * DM + t * 4) = w4;
}

// merged: embed (blocks 0..MR-1) + tok_emb bf16 conversion (rest)
__global__ __launch_bounds__(256) void embtok_k(const int* __restrict__ idx,
                                                const float* __restrict__ tok,
                                                const float* __restrict__ pos,
                                                float* __restrict__ x,
                                                u16* __restrict__ tokT) {
  int t = threadIdx.x;
  if (blockIdx.x < MR) {
    int row = blockIdx.x;
    int s = row & (SQ - 1);
    int id = idx[row];
    float4 a = *(const float4*)(tok + (size_t)id * DM + t * 4);
    float4 p = *(const float4*)(pos + (size_t)s * DM + t * 4);
    a.x += p.x; a.y += p.y; a.z += p.z; a.w += p.w;
    *(float4*)(x + (size_t)row * DM + t * 4) = a;
  } else {
    size_t r = blockIdx.x - MR;
    ushort4 w = {0, 0, 0, 0};
    if (r < NV) {
      float4 v = *(const float4*)(tok + r * DM + t * 4);
      w.x = f2b(v.x); w.y = f2b(v.y); w.z = f2b(v.z); w.w = f2b(v.w);
    }
    *(ushort4*)(tokT + r * DM + t * 4) = w;
  }
}

extern "C" void kernel_launch(void* const* d_in, const int* in_sizes, int n_in,
                              void* d_out, int out_size, void* d_ws,
                              size_t ws_size, hipStream_t stream) {
  const int* idx = (const int*)d_in[0];
  const float* tok = (const float*)d_in[1];
  const float* pos = (const float*)d_in[2];
  const float* Wq = (const float*)d_in[3];
  const float* Wk = (const float*)d_in[4];
  const float* Wv = (const float*)d_in[5];
  const float* Wo = (const float*)d_in[6];
  const float* bo = (const float*)d_in[7];
  const float* W1 = (const float*)d_in[8];
  const float* b1 = (const float*)d_in[9];
  const float* W2 = (const float*)d_in[10];
  const float* b2 = (const float*)d_in[11];
  const float* ln1s = (const float*)d_in[12];
  const float* ln1b = (const float*)d_in[13];
  const float* ln2s = (const float*)d_in[14];
  const float* ln2b = (const float*)d_in[15];
  const float* lnfs = (const float*)d_in[16];
  const float* lnfb = (const float*)d_in[17];
  float* out = (float*)d_out;

  char* w = (char*)d_ws;
  float* x = (float*)w;  w += (size_t)MR * DM * 4;
  u16* h = (u16*)w;      w += (size_t)MR * DM * 2;
  u16* qb = (u16*)w;     w += (size_t)MR * DM * 2;
  u16* kb = (u16*)w;     w += (size_t)MR * DM * 2;
  u16* vt = (u16*)w;     w += (size_t)NB * DM * SQ * 2;
  u16* ff = (u16*)w;     w += (size_t)MR * DF * 2;
  u16* wb = (u16*)w;     w += ((size_t)4 * DM * DM + 2 * (size_t)DM * DF) * 2;
  u16* tokT = (u16*)w;
  u16* cx = h;
  u16* wo_b = wb + (size_t)3 * DM * DM;
  u16* wb1 = wb + (size_t)4 * DM * DM;
  u16* wb2 = wb1 + (size_t)DM * DF;

  dim3 T(256);
  embtok_k<<<MR + NVP, T, 0, stream>>>(idx, tok, pos, x, tokT);
  for (int l = 0; l < LL; ++l) {
    size_t wo_ = (size_t)l * DM * DM;
    size_t w1_ = (size_t)l * DM * DF;
    transpln_k<<<5120, T, 0, stream>>>(Wq + wo_, Wk + wo_, Wv + wo_, Wo + wo_,
                                       W1 + w1_, W2 + w1_, wb, x, ln1s + l * DM,
                                       ln1b + l * DM, h);
    gemm_k<7, 64, 128, 5, 256, 3><<<768, T, 0, stream>>>(
        h, wb, qb, kb, vt, nullptr, 3 * DM, DM, DM, DM, DM);
    fattn_k<<<512, T, 0, stream>>>(qb, kb, vt, cx);
    gemm_k<1, 64, 64, 5, 256, 3><<<512, T, 0, stream>>>(
        cx, wo_b, x, nullptr, nullptr, bo + l * DM, DM, DM, DM, DM, DM);
    ln_k<<<MR, T, 0, stream>>>(x, ln2s + l * DM, ln2b + l * DM, h);
    gemm_k<2, 64, 128, 5, 256, 3><<<1024, T, 0, stream>>>(
        h, wb1, ff, nullptr, nullptr, b1 + l * DF, DF, DM, DM, DM, DF);
    gemm_k<1, 64, 64, 5, 256, 3><<<512, T, 0, stream>>>(
        ff, wb2, x, nullptr, nullptr, b2 + l * DM, DM, DF, DF, DF, DM);
  }
  ln_k<<<MR, T, 0, stream>>>(x, lnfs, lnfb, h);
  gemm_k<6, 256, 256, 3, 512, 2><<<1576, dim3(512), 0, stream>>>(
      h, tokT, out, nullptr, nullptr, nullptr, NV, DM, DM, DM, NV);
}

// Round 6
// 2435.093 us; speedup vs baseline: 1.0318x; 1.0318x over previous
//
#include <hip/hip_runtime.h>

// GPT-2 forward. Round 6: layer GEMMs = round-4 2-buffer structure (reverted);
// logits = 256²/8-wave paired-tile 4-phase counted-vmcnt schedule (T3/T4).

#define LL 12
#define DM 1024
#define NH 16
#define DHD 64
#define NV 50257
#define NVP 50432  // 197*256
#define SQ 512
#define NB 4
#define DF 4096
#define MR (NB * SQ)

typedef short bf16x8 __attribute__((ext_vector_type(8)));
typedef float f32x4 __attribute__((ext_vector_type(4)));
typedef unsigned short u16;

__device__ __forceinline__ u16 f2b(float f) {  // f32 -> bf16 RNE
  unsigned u = __float_as_uint(f);
  u += 0x7fff + ((u >> 16) & 1);
  return (u16)(u >> 16);
}

__device__ __forceinline__ void gload16(const u16* g, u16* l) {
  __builtin_amdgcn_global_load_lds(
      (const __attribute__((address_space(1))) unsigned*)g,
      (__attribute__((address_space(3))) unsigned*)l, 16, 0, 0);
}

// ---------------- layer GEMM (round-4 structure, 256 thr, 2-buffer) --------
// MODE 1: Cf32 += acc + bias   MODE 2: bf16 C = gelu(acc+bias)
// MODE 7: QKV fused (route n>>10), V transposed
template <int MODE, int TBM, int TBN, int MTLOG>
__global__ __launch_bounds__(256, 2) void gemm_k(
    const u16* __restrict__ A, const u16* __restrict__ B, void* __restrict__ Cp,
    void* __restrict__ Cp2, void* __restrict__ Cp3,
    const float* __restrict__ bias, int N, int K, int lda, int ldb, int ldc) {
  int id = blockIdx.x;
  int q8 = gridDim.x >> 3;
  int swz = (id & 7) * q8 + (id >> 3);
  int mt = swz & ((1 << MTLOG) - 1), nt = swz >> MTLOG;
  int m0 = mt * TBM, n0 = nt * TBN;

  __shared__ u16 As[2][TBM * 64];
  __shared__ u16 Bs[2][TBN * 64];

  int t = threadIdx.x, lane = t & 63, wave = t >> 6;
  int wm = wave >> 1, wn = wave & 1;
  int lr = lane & 15, g = lane >> 4;
  int srow = lane >> 3;
  int sxcol = ((lane & 7) ^ (lane >> 3)) << 3;  // inverse-swizzled global col
  int rsw = (lr & 7) << 3;                      // read-side XOR (u16 units)
  constexpr int FM = TBM / 32, FN = TBN / 32;
  constexpr int CA = TBM / 32, CB = TBN / 32;

  f32x4 acc[FM][FN];
#pragma unroll
  for (int i = 0; i < FM; ++i)
#pragma unroll
    for (int j = 0; j < FN; ++j) acc[i][j] = (f32x4){0.f, 0.f, 0.f, 0.f};

  auto stage = [&](int buf, int kt) {
    int k0 = kt * 64;
#pragma unroll
    for (int v = 0; v < CA; ++v) {
      int c = v * 4 + wave;
      gload16(A + (size_t)(m0 + c * 8 + srow) * lda + k0 + sxcol,
              &As[buf][c * 512]);
    }
#pragma unroll
    for (int v = 0; v < CB; ++v) {
      int c = v * 4 + wave;
      gload16(B + (size_t)(n0 + c * 8 + srow) * ldb + k0 + sxcol,
              &Bs[buf][c * 512]);
    }
  };

  auto compute = [&](int buf) {
    bf16x8 af[FM][2], bq[FN][2];
#pragma unroll
    for (int ks = 0; ks < 2; ++ks) {
      int co = (ks * 32 + g * 8) ^ rsw;
#pragma unroll
      for (int i = 0; i < FM; ++i)
        af[i][ks] =
            *(const bf16x8*)&As[buf][(wm * (TBM / 2) + i * 16 + lr) * 64 + co];
#pragma unroll
      for (int j = 0; j < FN; ++j)
        bq[j][ks] =
            *(const bf16x8*)&Bs[buf][(wn * (TBN / 2) + j * 16 + lr) * 64 + co];
    }
#pragma unroll
    for (int ks = 0; ks < 2; ++ks)
#pragma unroll
      for (int i = 0; i < FM; ++i)
#pragma unroll
        for (int j = 0; j < FN; ++j)
          acc[i][j] = __builtin_amdgcn_mfma_f32_16x16x32_bf16(
              af[i][ks], bq[j][ks], acc[i][j], 0, 0, 0);
  };

  int nk = K >> 6;
  stage(0, 0);
  __syncthreads();
  int cur = 0;
  for (int kt = 0; kt < nk - 1; ++kt) {
    stage(cur ^ 1, kt + 1);
    compute(cur);
    __syncthreads();
    cur ^= 1;
  }
  compute(cur);

  int rb = g * 4;
#pragma unroll
  for (int i = 0; i < FM; ++i) {
#pragma unroll
    for (int j = 0; j < FN; ++j) {
      int m = m0 + wm * (TBM / 2) + i * 16 + rb;
      int n = n0 + wn * (TBN / 2) + j * 16 + lr;
      f32x4 a = acc[i][j];
      if constexpr (MODE == 1) {
        float* C = (float*)Cp;
        float bv = bias[n];
#pragma unroll
        for (int r = 0; r < 4; ++r) {
          size_t ix = (size_t)(m + r) * ldc + n;
          C[ix] += a[r] + bv;
        }
      } else if constexpr (MODE == 2) {
        u16* C = (u16*)Cp;
        float bv = bias[n];
#pragma unroll
        for (int r = 0; r < 4; ++r) {
          float u2 = a[r] + bv;
          float gl =
              0.5f * u2 *
              (1.f + tanhf(0.7978845608f * (u2 + 0.044715f * u2 * u2 * u2)));
          C[(size_t)(m + r) * ldc + n] = f2b(gl);
        }
      } else if constexpr (MODE == 7) {
        int sel = n >> 10, nn = n & 1023;
        if (sel < 2) {
          u16* C = sel == 0 ? (u16*)Cp : (u16*)Cp2;
#pragma unroll
          for (int r = 0; r < 4; ++r) C[(size_t)(m + r) * ldc + nn] = f2b(a[r]);
        } else {  // V transposed: vt[b][d][s]
          u16* C = (u16*)Cp3;
          int bb = m >> 9, s2 = m & (SQ - 1);
          ushort4 w4;
          w4.x = f2b(a[0]); w4.y = f2b(a[1]);
          w4.z = f2b(a[2]); w4.w = f2b(a[3]);
          *(ushort4*)&C[((size_t)bb * DM + nn) * SQ + s2] = w4;
        }
      }
    }
  }
}

// ------- logits GEMM: 256x256, 512 thr (2Mx4N waves), 4-phase counted -------
// Paired K-tiles in 2 LDS slots; per tile: 2 phases of {12 ds_read_b128 +
// 32 MFMA}; slot refill issued right after slot's closing barrier; vmcnt(8)
// in-loop (8 = loads/slot/wave), vmcnt(0) only for the final tile.
__global__ __launch_bounds__(512, 2) void gemmL_k(const u16* __restrict__ A,
                                                  const u16* __restrict__ B,
                                                  float* __restrict__ C) {
  int id = blockIdx.x;
  int q8 = gridDim.x >> 3;
  int swz = (id & 7) * q8 + (id >> 3);
  int mt = swz & 7, nt = swz >> 3;
  int m0 = mt * 256, n0 = nt * 256;

  __shared__ u16 As[2][256 * 64];
  __shared__ u16 Bs[2][256 * 64];

  int t = threadIdx.x, lane = t & 63, wave = t >> 6;
  int wm = wave >> 2, wn = wave & 3;
  int lr = lane & 15, g = lane >> 4;
  int rsw = (lr & 7) << 3;

  f32x4 acc[8][4];
#pragma unroll
  for (int i = 0; i < 8; ++i)
#pragma unroll
    for (int j = 0; j < 4; ++j) acc[i][j] = (f32x4){0.f, 0.f, 0.f, 0.f};

  // stage whole slot: 8 gload16/thread (A:4, B:4); source col pre-swizzled
  auto stage = [&](int slot, int kt) {
    int k0 = kt * 64;
#pragma unroll
    for (int v = 0; v < 4; ++v) {
      int c = v * 512 + t;
      int row = c >> 3, cc = c & 7;
      gload16(A + (size_t)(m0 + row) * DM + k0 + ((cc ^ (row & 7)) << 3),
              &As[slot][c * 8]);
    }
#pragma unroll
    for (int v = 0; v < 4; ++v) {
      int c = v * 512 + t;
      int row = c >> 3, cc = c & 7;
      gload16(B + (size_t)(n0 + row) * DM + k0 + ((cc ^ (row & 7)) << 3),
              &Bs[slot][c * 8]);
    }
  };

  auto phase = [&](int slot, int ks) {
    int co = (ks * 32 + g * 8) ^ rsw;
    bf16x8 af[8], bq[4];
#pragma unroll
    for (int i = 0; i < 8; ++i)
      af[i] = *(const bf16x8*)&As[slot][(wm * 128 + i * 16 + lr) * 64 + co];
#pragma unroll
    for (int j = 0; j < 4; ++j)
      bq[j] = *(const bf16x8*)&Bs[slot][(wn * 64 + j * 16 + lr) * 64 + co];
    __builtin_amdgcn_s_setprio(1);
#pragma unroll
    for (int i = 0; i < 8; ++i)
#pragma unroll
      for (int j = 0; j < 4; ++j)
        acc[i][j] = __builtin_amdgcn_mfma_f32_16x16x32_bf16(af[i], bq[j],
                                                            acc[i][j], 0, 0, 0);
    __builtin_amdgcn_s_setprio(0);
  };

  constexpr int NIT = DM / 128;  // 8 iterations, 2 K-tiles each
  stage(0, 0);
  stage(1, 1);
#pragma unroll 1
  for (int it = 0; it < NIT; ++it) {
    // slot0 (tile 2it): its 8 loads are oldest -> vmcnt(8) lands them
    asm volatile("s_waitcnt vmcnt(8)" ::: "memory");
    __builtin_amdgcn_s_barrier();
    phase(0, 0);
    phase(0, 1);
    __builtin_amdgcn_s_barrier();  // all waves done reading slot0
    if (it + 1 < NIT) {
      stage(0, 2 * it + 2);  // refill in the shadow of slot1's compute
      asm volatile("s_waitcnt vmcnt(8)" ::: "memory");  // slot1 loads landed
    } else {
      asm volatile("s_waitcnt vmcnt(0)" ::: "memory");  // final tile: drain
    }
    __builtin_amdgcn_s_barrier();
    phase(1, 0);
    phase(1, 1);
    __builtin_amdgcn_s_barrier();  // all waves done reading slot1
    if (it + 1 < NIT) stage(1, 2 * it + 3);
  }

  int rb = g * 4;
#pragma unroll
  for (int i = 0; i < 8; ++i) {
#pragma unroll
    for (int j = 0; j < 4; ++j) {
      int m = m0 + wm * 128 + i * 16 + rb;
      int n = n0 + wn * 64 + j * 16 + lr;
      if (n < NV) {
        f32x4 a = acc[i][j];
#pragma unroll
        for (int r = 0; r < 4; ++r) C[(size_t)(m + r) * NV + n] = a[r];
      }
    }
  }
}

// -------- flash attention: one block = (qt 64 q-rows, b,h); 4 waves ---------
__global__ __launch_bounds__(256) void fattn_k(const u16* __restrict__ qb,
                                               const u16* __restrict__ kb,
                                               const u16* __restrict__ vt,
                                               u16* __restrict__ cx) {
  int id = blockIdx.x;
  int qt = id >> 6, bh = id & 63;
  int b = bh >> 4, hh = bh & 15;
  int t = threadIdx.x, lane = t & 63, w = t >> 6;
  int lr = lane & 15, g = lane >> 4;

  __shared__ u16 Kt[64 * 72];
  __shared__ u16 Vt[64 * 72];
  __shared__ u16 Pl[4 * 16 * 72];

  int qw = qt * 64 + w * 16;

  bf16x8 aQ[2];
#pragma unroll
  for (int f = 0; f < 2; ++f)
    aQ[f] = *(const bf16x8*)&qb[(size_t)(b * SQ + qw + lr) * DM + hh * DHD +
                                f * 32 + g * 8];

  f32x4 o[4];
#pragma unroll
  for (int j = 0; j < 4; ++j) o[j] = (f32x4){0.f, 0.f, 0.f, 0.f};
  f32x4 m4 = (f32x4){-3e38f, -3e38f, -3e38f, -3e38f};
  f32x4 l4 = (f32x4){0.f, 0.f, 0.f, 0.f};
  u16* Pw = &Pl[w * 16 * 72];

  for (int kt = 0; kt <= qt; ++kt) {
    int k0 = kt * 64;
#pragma unroll
    for (int it = 0; it < 2; ++it) {
      int c = t + it * 256;
      int row = c >> 3, ch = c & 7;
      int4 kv = *(const int4*)&kb[(size_t)(b * SQ + k0 + row) * DM + hh * DHD +
                                  ch * 8];
      int4 vv = *(const int4*)&vt[(size_t)(b * DM + hh * DHD + row) * SQ + k0 +
                                  ch * 8];
      *(int4*)&Kt[row * 72 + ch * 8] = kv;
      *(int4*)&Vt[row * 72 + ch * 8] = vv;
    }
    __syncthreads();

    f32x4 s[4];
#pragma unroll
    for (int j = 0; j < 4; ++j) s[j] = (f32x4){0.f, 0.f, 0.f, 0.f};
#pragma unroll
    for (int j = 0; j < 4; ++j)
#pragma unroll
      for (int f = 0; f < 2; ++f) {
        bf16x8 bk = *(const bf16x8*)&Kt[(j * 16 + lr) * 72 + f * 32 + g * 8];
        s[j] =
            __builtin_amdgcn_mfma_f32_16x16x32_bf16(aQ[f], bk, s[j], 0, 0, 0);
      }
#pragma unroll
    for (int j = 0; j < 4; ++j) {
      int kcol = k0 + j * 16 + lr;
#pragma unroll
      for (int r = 0; r < 4; ++r) {
        float sv = s[j][r] * 0.125f;
        if (kt == qt && kcol > qw + g * 4 + r) sv = -1e30f;
        s[j][r] = sv;
      }
    }
    f32x4 fr;
#pragma unroll
    for (int r = 0; r < 4; ++r) {
      float v = fmaxf(fmaxf(s[0][r], s[1][r]), fmaxf(s[2][r], s[3][r]));
#pragma unroll
      for (int d = 1; d < 16; d <<= 1) v = fmaxf(v, __shfl_xor(v, d));
      float mn = fmaxf(m4[r], v);
      fr[r] = __expf(m4[r] - mn);
      m4[r] = mn;
    }
#pragma unroll
    for (int j = 0; j < 4; ++j)
#pragma unroll
      for (int r = 0; r < 4; ++r) o[j][r] *= fr[r];
    f32x4 ps = (f32x4){0.f, 0.f, 0.f, 0.f};
#pragma unroll
    for (int j = 0; j < 4; ++j)
#pragma unroll
      for (int r = 0; r < 4; ++r) {
        float p = __expf(s[j][r] - m4[r]);
        s[j][r] = p;
        ps[r] += p;
      }
#pragma unroll
    for (int r = 0; r < 4; ++r) {
      float v = ps[r];
#pragma unroll
      for (int d = 1; d < 16; d <<= 1) v += __shfl_xor(v, d);
      l4[r] = l4[r] * fr[r] + v;
    }
#pragma unroll
    for (int j = 0; j < 4; ++j)
#pragma unroll
      for (int r = 0; r < 4; ++r)
        Pw[(g * 4 + r) * 72 + j * 16 + lr] = f2b(s[j][r]);
#pragma unroll
    for (int f = 0; f < 2; ++f) {
      bf16x8 ap = *(const bf16x8*)&Pw[lr * 72 + f * 32 + g * 8];
#pragma unroll
      for (int j = 0; j < 4; ++j) {
        bf16x8 bv = *(const bf16x8*)&Vt[(j * 16 + lr) * 72 + f * 32 + g * 8];
        o[j] = __builtin_amdgcn_mfma_f32_16x16x32_bf16(ap, bv, o[j], 0, 0, 0);
      }
    }
    __syncthreads();
  }

#pragma unroll
  for (int r = 0; r < 4; ++r) {
    float inv = 1.f / l4[r];
#pragma unroll
    for (int j = 0; j < 4; ++j)
      cx[(size_t)(b * SQ + qw + g * 4 + r) * DM + hh * DHD + j * 16 + lr] =
          f2b(o[j][r] * inv);
  }
}

// ---- merged: weight transpose (blocks 0..3071) + ln1 (blocks 3072..5119) ---
__global__ __launch_bounds__(256) void transpln_k(
    const float* __restrict__ Wq, const float* __restrict__ Wk,
    const float* __restrict__ Wv, const float* __restrict__ Wo,
    const float* __restrict__ W1, const float* __restrict__ W2,
    u16* __restrict__ wb, const float* __restrict__ x,
    const float* __restrict__ sc, const float* __restrict__ sh,
    u16* __restrict__ o) {
  __shared__ u16 tl[64][72];
  __shared__ float red[8];
  int t = threadIdx.x;
  if (blockIdx.x < 3072) {
    int id = blockIdx.x;
    const float* src;
    u16* dst;
    int K, N, ktile, ntile;
    if (id < 1024) {
      int mat = id >> 8, rem = id & 255;
      ntile = rem & 15; ktile = rem >> 4;
      src = mat == 0 ? Wq : mat == 1 ? Wk : mat == 2 ? Wv : Wo;
      dst = wb + (size_t)mat * DM * DM;
      K = DM; N = DM;
    } else if (id < 2048) {
      int rem = id - 1024;
      ntile = rem & 63; ktile = rem >> 6;
      src = W1; dst = wb + (size_t)4 * DM * DM;
      K = DM; N = DF;
    } else {
      int rem = id - 2048;
      ntile = rem & 15; ktile = rem >> 4;
      src = W2; dst = wb + (size_t)4 * DM * DM + (size_t)DM * DF;
      K = DF; N = DM;
    }
    int n0 = ntile * 64, k0 = ktile * 64;
    int tn = (t & 15) * 4, tk = t >> 4;
#pragma unroll
    for (int it = 0; it < 4; ++it) {
      int k = tk + it * 16;
      float4 v = *(const float4*)(src + (size_t)(k0 + k) * N + n0 + tn);
      tl[tn + 0][k] = f2b(v.x);
      tl[tn + 1][k] = f2b(v.y);
      tl[tn + 2][k] = f2b(v.z);
      tl[tn + 3][k] = f2b(v.w);
    }
    __syncthreads();
    int wn = t >> 3, wk = (t & 7) * 8;
#pragma unroll
    for (int it = 0; it < 2; ++it) {
      int n = wn + it * 32;
      int4 v = *(const int4*)&tl[n][wk];
      *(int4*)(dst + (size_t)(n0 + n) * K + k0 + wk) = v;
    }
  } else {
    int row = blockIdx.x - 3072;
    const float* xr = x + (size_t)row * DM;
    float4 v = *(const float4*)(xr + t * 4);
    float s = v.x + v.y + v.z + v.w;
#pragma unroll
    for (int d = 32; d; d >>= 1) s += __shfl_xor(s, d);
    if ((t & 63) == 0) red[t >> 6] = s;
    __syncthreads();
    float mean = (red[0] + red[1] + red[2] + red[3]) * (1.f / DM);
    float dx = v.x - mean, dy = v.y - mean, dz = v.z - mean, dw = v.w - mean;
    float s2 = dx * dx + dy * dy + dz * dz + dw * dw;
#pragma unroll
    for (int d = 32; d; d >>= 1) s2 += __shfl_xor(s2, d);
    if ((t & 63) == 0) red[4 + (t >> 6)] = s2;
    __syncthreads();
    float var = (red[4] + red[5] + red[6] + red[7]) * (1.f / DM);
    float rstd = 1.f / sqrtf(var + 1e-6f);
    float4 gg = *(const float4*)(sc + t * 4);
    float4 b = *(const float4*)(sh + t * 4);
    ushort4 w4;
    w4.x = f2b(gg.x * (dx * rstd) + b.x);
    w4.y = f2b(gg.y * (dy * rstd) + b.y);
    w4.z = f2b(gg.z * (dz * rstd) + b.z);
    w4.w = f2b(gg.w * (dw * rstd) + b.w);
    *(ushort4*)(o + (size_t)row * DM + t * 4) = w4;
  }
}

__global__ __launch_bounds__(256) void ln_k(const float* __restrict__ x,
                                            const float* __restrict__ sc,
                                            const float* __restrict__ sh,
                                            u16* __restrict__ o) {
  int row = blockIdx.x, t = threadIdx.x;
  const float* xr = x + (size_t)row * DM;
  float4 v = *(const float4*)(xr + t * 4);
  float s = v.x + v.y + v.z + v.w;
#pragma unroll
  for (int d = 32; d; d >>= 1) s += __shfl_xor(s, d);
  __shared__ float red[8];
  if ((t & 63) == 0) red[t >> 6] = s;
  __syncthreads();
  float mean = (red[0] + red[1] + red[2] + red[3]) * (1.f / DM);
  float dx = v.x - mean, dy = v.y - mean, dz = v.z - mean, dw = v.w - mean;
  float s2 = dx * dx + dy * dy + dz * dz + dw * dw;
#pragma unroll
  for (int d = 32; d; d >>= 1) s2 += __shfl_xor(s2, d);
  if ((t & 63) == 0) red[4 + (t >> 6)] = s2;
  __syncthreads();
  float var = (red[4] + red[5] + red[6] + red[7]) * (1.f / DM);
  float rstd = 1.f / sqrtf(var + 1e-6f);
  float4 g = *(const float4*)(sc + t * 4);
  float4 b = *(const float4*)(sh + t * 4);
  ushort4 w4;
  w4.x = f2b(g.x * (dx * rstd) + b.x);
  w4.y = f2b(g.y * (dy * rstd) + b.y);
  w4.z = f2b(g.z * (dz * rstd) + b.z);
  w4.w = f2b(g.w * (dw * rstd) + b.w);
  *(ushort4*)(o + (size_t)row * DM + t * 4) = w4;
}

// merged: embed (blocks 0..MR-1) + tok_emb bf16 conversion (rest)
__global__ __launch_bounds__(256) void embtok_k(const int* __restrict__ idx,
                                                const float* __restrict__ tok,
                                                const float* __restrict__ pos,
                                                float* __restrict__ x,
                                                u16* __restrict__ tokT) {
  int t = threadIdx.x;
  if (blockIdx.x < MR) {
    int row = blockIdx.x;
    int s = row & (SQ - 1);
    int id = idx[row];
    float4 a = *(const float4*)(tok + (size_t)id * DM + t * 4);
    float4 p = *(const float4*)(pos + (size_t)s * DM + t * 4);
    a.x += p.x; a.y += p.y; a.z += p.z; a.w += p.w;
    *(float4*)(x + (size_t)row * DM + t * 4) = a;
  } else {
    size_t r = blockIdx.x - MR;
    ushort4 w = {0, 0, 0, 0};
    if (r < NV) {
      float4 v = *(const float4*)(tok + r * DM + t * 4);
      w.x = f2b(v.x); w.y = f2b(v.y); w.z = f2b(v.z); w.w = f2b(v.w);
    }
    *(ushort4*)(tokT + r * DM + t * 4) = w;
  }
}

extern "C" void kernel_launch(void* const* d_in, const int* in_sizes, int n_in,
                              void* d_out, int out_size, void* d_ws,
                              size_t ws_size, hipStream_t stream) {
  const int* idx = (const int*)d_in[0];
  const float* tok = (const float*)d_in[1];
  const float* pos = (const float*)d_in[2];
  const float* Wq = (const float*)d_in[3];
  const float* Wk = (const float*)d_in[4];
  const float* Wv = (const float*)d_in[5];
  const float* Wo = (const float*)d_in[6];
  const float* bo = (const float*)d_in[7];
  const float* W1 = (const float*)d_in[8];
  const float* b1 = (const float*)d_in[9];
  const float* W2 = (const float*)d_in[10];
  const float* b2 = (const float*)d_in[11];
  const float* ln1s = (const float*)d_in[12];
  const float* ln1b = (const float*)d_in[13];
  const float* ln2s = (const float*)d_in[14];
  const float* ln2b = (const float*)d_in[15];
  const float* lnfs = (const float*)d_in[16];
  const float* lnfb = (const float*)d_in[17];
  float* out = (float*)d_out;

  char* w = (char*)d_ws;
  float* x = (float*)w;  w += (size_t)MR * DM * 4;
  u16* h = (u16*)w;      w += (size_t)MR * DM * 2;
  u16* qb = (u16*)w;     w += (size_t)MR * DM * 2;
  u16* kb = (u16*)w;     w += (size_t)MR * DM * 2;
  u16* vt = (u16*)w;     w += (size_t)NB * DM * SQ * 2;
  u16* ff = (u16*)w;     w += (size_t)MR * DF * 2;
  u16* wb = (u16*)w;     w += ((size_t)4 * DM * DM + 2 * (size_t)DM * DF) * 2;
  u16* tokT = (u16*)w;
  u16* cx = h;
  u16* wo_b = wb + (size_t)3 * DM * DM;
  u16* wb1 = wb + (size_t)4 * DM * DM;
  u16* wb2 = wb1 + (size_t)DM * DF;

  dim3 T(256);
  embtok_k<<<MR + NVP, T, 0, stream>>>(idx, tok, pos, x, tokT);
  for (int l = 0; l < LL; ++l) {
    size_t wo_ = (size_t)l * DM * DM;
    size_t w1_ = (size_t)l * DM * DF;
    transpln_k<<<5120, T, 0, stream>>>(Wq + wo_, Wk + wo_, Wv + wo_, Wo + wo_,
                                       W1 + w1_, W2 + w1_, wb, x, ln1s + l * DM,
                                       ln1b + l * DM, h);
    gemm_k<7, 64, 128, 5><<<768, T, 0, stream>>>(
        h, wb, qb, kb, vt, nullptr, 3 * DM, DM, DM, DM, DM);
    fattn_k<<<512, T, 0, stream>>>(qb, kb, vt, cx);
    gemm_k<1, 64, 64, 5><<<512, T, 0, stream>>>(
        cx, wo_b, x, nullptr, nullptr, bo + l * DM, DM, DM, DM, DM, DM);
    ln_k<<<MR, T, 0, stream>>>(x, ln2s + l * DM, ln2b + l * DM, h);
    gemm_k<2, 128, 128, 4><<<512, T, 0, stream>>>(
        h, wb1, ff, nullptr, nullptr, b1 + l * DF, DF, DM, DM, DM, DF);
    gemm_k<1, 64, 64, 5><<<512, T, 0, stream>>>(
        ff, wb2, x, nullptr, nullptr, b2 + l * DM, DM, DF, DF, DF, DM);
  }
  ln_k<<<MR, T, 0, stream>>>(x, lnfs, lnfb, h);
  gemmL_k<<<1576, dim3(512), 0, stream>>>(h, tokT, out);
}

// Round 7
// 2247.810 us; speedup vs baseline: 1.1178x; 1.0833x over previous
//
#include <hip/hip_runtime.h>

// GPT-2 forward. Round 7: layers = round-4/6 structure (unchanged).
// Logits = 256²/8-wave with ASYMMETRIC-DEPTH counted pipeline:
// A 2-deep (L2-hot), B 3-deep (HBM stream, ~900cyc coverage), 160KB LDS.

#define LL 12
#define DM 1024
#define NH 16
#define DHD 64
#define NV 50257
#define NVP 50432  // 197*256
#define SQ 512
#define NB 4
#define DF 4096
#define MR (NB * SQ)

typedef short bf16x8 __attribute__((ext_vector_type(8)));
typedef float f32x4 __attribute__((ext_vector_type(4)));
typedef unsigned short u16;

__device__ __forceinline__ u16 f2b(float f) {  // f32 -> bf16 RNE
  unsigned u = __float_as_uint(f);
  u += 0x7fff + ((u >> 16) & 1);
  return (u16)(u >> 16);
}

__device__ __forceinline__ void gload16(const u16* g, u16* l) {
  __builtin_amdgcn_global_load_lds(
      (const __attribute__((address_space(1))) unsigned*)g,
      (__attribute__((address_space(3))) unsigned*)l, 16, 0, 0);
}

// ---------------- layer GEMM (round-4 structure, 256 thr, 2-buffer) --------
// MODE 1: Cf32 += acc + bias   MODE 2: bf16 C = gelu(acc+bias)
// MODE 7: QKV fused (route n>>10), V transposed
template <int MODE, int TBM, int TBN, int MTLOG>
__global__ __launch_bounds__(256, 2) void gemm_k(
    const u16* __restrict__ A, const u16* __restrict__ B, void* __restrict__ Cp,
    void* __restrict__ Cp2, void* __restrict__ Cp3,
    const float* __restrict__ bias, int N, int K, int lda, int ldb, int ldc) {
  int id = blockIdx.x;
  int q8 = gridDim.x >> 3;
  int swz = (id & 7) * q8 + (id >> 3);
  int mt = swz & ((1 << MTLOG) - 1), nt = swz >> MTLOG;
  int m0 = mt * TBM, n0 = nt * TBN;

  __shared__ u16 As[2][TBM * 64];
  __shared__ u16 Bs[2][TBN * 64];

  int t = threadIdx.x, lane = t & 63, wave = t >> 6;
  int wm = wave >> 1, wn = wave & 1;
  int lr = lane & 15, g = lane >> 4;
  int srow = lane >> 3;
  int sxcol = ((lane & 7) ^ (lane >> 3)) << 3;  // inverse-swizzled global col
  int rsw = (lr & 7) << 3;                      // read-side XOR (u16 units)
  constexpr int FM = TBM / 32, FN = TBN / 32;
  constexpr int CA = TBM / 32, CB = TBN / 32;

  f32x4 acc[FM][FN];
#pragma unroll
  for (int i = 0; i < FM; ++i)
#pragma unroll
    for (int j = 0; j < FN; ++j) acc[i][j] = (f32x4){0.f, 0.f, 0.f, 0.f};

  auto stage = [&](int buf, int kt) {
    int k0 = kt * 64;
#pragma unroll
    for (int v = 0; v < CA; ++v) {
      int c = v * 4 + wave;
      gload16(A + (size_t)(m0 + c * 8 + srow) * lda + k0 + sxcol,
              &As[buf][c * 512]);
    }
#pragma unroll
    for (int v = 0; v < CB; ++v) {
      int c = v * 4 + wave;
      gload16(B + (size_t)(n0 + c * 8 + srow) * ldb + k0 + sxcol,
              &Bs[buf][c * 512]);
    }
  };

  auto compute = [&](int buf) {
    bf16x8 af[FM][2], bq[FN][2];
#pragma unroll
    for (int ks = 0; ks < 2; ++ks) {
      int co = (ks * 32 + g * 8) ^ rsw;
#pragma unroll
      for (int i = 0; i < FM; ++i)
        af[i][ks] =
            *(const bf16x8*)&As[buf][(wm * (TBM / 2) + i * 16 + lr) * 64 + co];
#pragma unroll
      for (int j = 0; j < FN; ++j)
        bq[j][ks] =
            *(const bf16x8*)&Bs[buf][(wn * (TBN / 2) + j * 16 + lr) * 64 + co];
    }
#pragma unroll
    for (int ks = 0; ks < 2; ++ks)
#pragma unroll
      for (int i = 0; i < FM; ++i)
#pragma unroll
        for (int j = 0; j < FN; ++j)
          acc[i][j] = __builtin_amdgcn_mfma_f32_16x16x32_bf16(
              af[i][ks], bq[j][ks], acc[i][j], 0, 0, 0);
  };

  int nk = K >> 6;
  stage(0, 0);
  __syncthreads();
  int cur = 0;
  for (int kt = 0; kt < nk - 1; ++kt) {
    stage(cur ^ 1, kt + 1);
    compute(cur);
    __syncthreads();
    cur ^= 1;
  }
  compute(cur);

  int rb = g * 4;
#pragma unroll
  for (int i = 0; i < FM; ++i) {
#pragma unroll
    for (int j = 0; j < FN; ++j) {
      int m = m0 + wm * (TBM / 2) + i * 16 + rb;
      int n = n0 + wn * (TBN / 2) + j * 16 + lr;
      f32x4 a = acc[i][j];
      if constexpr (MODE == 1) {
        float* C = (float*)Cp;
        float bv = bias[n];
#pragma unroll
        for (int r = 0; r < 4; ++r) {
          size_t ix = (size_t)(m + r) * ldc + n;
          C[ix] += a[r] + bv;
        }
      } else if constexpr (MODE == 2) {
        u16* C = (u16*)Cp;
        float bv = bias[n];
#pragma unroll
        for (int r = 0; r < 4; ++r) {
          float u2 = a[r] + bv;
          float gl =
              0.5f * u2 *
              (1.f + tanhf(0.7978845608f * (u2 + 0.044715f * u2 * u2 * u2)));
          C[(size_t)(m + r) * ldc + n] = f2b(gl);
        }
      } else if constexpr (MODE == 7) {
        int sel = n >> 10, nn = n & 1023;
        if (sel < 2) {
          u16* C = sel == 0 ? (u16*)Cp : (u16*)Cp2;
#pragma unroll
          for (int r = 0; r < 4; ++r) C[(size_t)(m + r) * ldc + nn] = f2b(a[r]);
        } else {  // V transposed: vt[b][d][s]
          u16* C = (u16*)Cp3;
          int bb = m >> 9, s2 = m & (SQ - 1);
          ushort4 w4;
          w4.x = f2b(a[0]); w4.y = f2b(a[1]);
          w4.z = f2b(a[2]); w4.w = f2b(a[3]);
          *(ushort4*)&C[((size_t)bb * DM + nn) * SQ + s2] = w4;
        }
      }
    }
  }
}

// ------- logits GEMM: 256x256, 8 waves, asymmetric-depth counted pipeline ---
// A 2-deep (64KB), B 3-deep (96KB) = 160KB LDS, 1 block/CU. Issue stream
// B0,A0,B1,A1,B2 then per-iter {A(t+2), B(t+3)}: vmcnt(12) lands {B(t),A(t)};
// B prefetch distance ~2.5 iters (~800cyc MFMA) covers HBM stream latency.
// K = 1024 -> 16 tiles, tail peeled (waits 12..12, 8, 0).
__global__ __launch_bounds__(512, 1) void gemmL_k(const u16* __restrict__ A,
                                                  const u16* __restrict__ B,
                                                  float* __restrict__ C) {
  int id = blockIdx.x;
  int q8 = gridDim.x >> 3;
  int swz = (id & 7) * q8 + (id >> 3);
  int mt = swz & 7, nt = swz >> 3;
  int m0 = mt * 256, n0 = nt * 256;

  __shared__ u16 As[2][256 * 64];  // 64 KB
  __shared__ u16 Bs[3][256 * 64];  // 96 KB

  int t = threadIdx.x, lane = t & 63, wave = t >> 6;
  int wm = wave >> 2, wn = wave & 3;  // 2M x 4N; wave tile 128x64
  int lr = lane & 15, g = lane >> 4;
  int rsw = (lr & 7) << 3;

  f32x4 acc[8][4];
#pragma unroll
  for (int i = 0; i < 8; ++i)
#pragma unroll
    for (int j = 0; j < 4; ++j) acc[i][j] = (f32x4){0.f, 0.f, 0.f, 0.f};

  auto stageA = [&](int slot, int kt) {  // 4 gload16/thread
    int k0 = kt * 64;
#pragma unroll
    for (int v = 0; v < 4; ++v) {
      int c = v * 512 + t;
      int row = c >> 3, cc = c & 7;
      gload16(A + (size_t)(m0 + row) * DM + k0 + ((cc ^ (row & 7)) << 3),
              &As[slot][c * 8]);
    }
  };
  auto stageB = [&](int slot, int kt) {
    int k0 = kt * 64;
#pragma unroll
    for (int v = 0; v < 4; ++v) {
      int c = v * 512 + t;
      int row = c >> 3, cc = c & 7;
      gload16(B + (size_t)(n0 + row) * DM + k0 + ((cc ^ (row & 7)) << 3),
              &Bs[slot][c * 8]);
    }
  };
  auto compute = [&](int sa, int sb) {
#pragma unroll
    for (int ks = 0; ks < 2; ++ks) {
      int co = (ks * 32 + g * 8) ^ rsw;
      bf16x8 af[8], bq[4];
#pragma unroll
      for (int i = 0; i < 8; ++i)
        af[i] = *(const bf16x8*)&As[sa][(wm * 128 + i * 16 + lr) * 64 + co];
#pragma unroll
      for (int j = 0; j < 4; ++j)
        bq[j] = *(const bf16x8*)&Bs[sb][(wn * 64 + j * 16 + lr) * 64 + co];
      __builtin_amdgcn_s_setprio(1);
#pragma unroll
      for (int i = 0; i < 8; ++i)
#pragma unroll
        for (int j = 0; j < 4; ++j)
          acc[i][j] = __builtin_amdgcn_mfma_f32_16x16x32_bf16(
              af[i], bq[j], acc[i][j], 0, 0, 0);
      __builtin_amdgcn_s_setprio(0);
    }
  };

  // prologue: B0,A0,B1,A1,B2 (20 loads outstanding/wave)
  stageB(0, 0); stageA(0, 0); stageB(1, 1); stageA(1, 1); stageB(2, 2);
  int sb = 0;
#pragma unroll 1
  for (int kt = 0; kt < 14; ++kt) {
    asm volatile("s_waitcnt vmcnt(12)" ::: "memory");  // B(kt),A(kt) landed
    __builtin_amdgcn_s_barrier();
    __builtin_amdgcn_sched_barrier(0);
    compute(kt & 1, sb);
    __builtin_amdgcn_s_barrier();
    __builtin_amdgcn_sched_barrier(0);
    stageA(kt & 1, kt + 2);              // refill just-read A slot
    if (kt < 13) stageB(sb, kt + 3);     // refill just-read B slot
    sb = sb + 1 == 3 ? 0 : sb + 1;
  }
  // kt=14: outstanding B14,A14,B15,A15 -> wait(8) lands B14,A14
  asm volatile("s_waitcnt vmcnt(8)" ::: "memory");
  __builtin_amdgcn_s_barrier();
  __builtin_amdgcn_sched_barrier(0);
  compute(0, 2);
  __builtin_amdgcn_s_barrier();
  __builtin_amdgcn_sched_barrier(0);
  // kt=15: drain
  asm volatile("s_waitcnt vmcnt(0)" ::: "memory");
  __builtin_amdgcn_s_barrier();
  __builtin_amdgcn_sched_barrier(0);
  compute(1, 0);

  int rb = g * 4;
#pragma unroll
  for (int i = 0; i < 8; ++i) {
#pragma unroll
    for (int j = 0; j < 4; ++j) {
      int m = m0 + wm * 128 + i * 16 + rb;
      int n = n0 + wn * 64 + j * 16 + lr;
      if (n < NV) {
        f32x4 a = acc[i][j];
#pragma unroll
        for (int r = 0; r < 4; ++r) C[(size_t)(m + r) * NV + n] = a[r];
      }
    }
  }
}

// -------- flash attention: one block = (qt 64 q-rows, b,h); 4 waves ---------
__global__ __launch_bounds__(256) void fattn_k(const u16* __restrict__ qb,
                                               const u16* __restrict__ kb,
                                               const u16* __restrict__ vt,
                                               u16* __restrict__ cx) {
  int id = blockIdx.x;
  int qt = id >> 6, bh = id & 63;
  int b = bh >> 4, hh = bh & 15;
  int t = threadIdx.x, lane = t & 63, w = t >> 6;
  int lr = lane & 15, g = lane >> 4;

  __shared__ u16 Kt[64 * 72];
  __shared__ u16 Vt[64 * 72];
  __shared__ u16 Pl[4 * 16 * 72];

  int qw = qt * 64 + w * 16;

  bf16x8 aQ[2];
#pragma unroll
  for (int f = 0; f < 2; ++f)
    aQ[f] = *(const bf16x8*)&qb[(size_t)(b * SQ + qw + lr) * DM + hh * DHD +
                                f * 32 + g * 8];

  f32x4 o[4];
#pragma unroll
  for (int j = 0; j < 4; ++j) o[j] = (f32x4){0.f, 0.f, 0.f, 0.f};
  f32x4 m4 = (f32x4){-3e38f, -3e38f, -3e38f, -3e38f};
  f32x4 l4 = (f32x4){0.f, 0.f, 0.f, 0.f};
  u16* Pw = &Pl[w * 16 * 72];

  for (int kt = 0; kt <= qt; ++kt) {
    int k0 = kt * 64;
#pragma unroll
    for (int it = 0; it < 2; ++it) {
      int c = t + it * 256;
      int row = c >> 3, ch = c & 7;
      int4 kv = *(const int4*)&kb[(size_t)(b * SQ + k0 + row) * DM + hh * DHD +
                                  ch * 8];
      int4 vv = *(const int4*)&vt[(size_t)(b * DM + hh * DHD + row) * SQ + k0 +
                                  ch * 8];
      *(int4*)&Kt[row * 72 + ch * 8] = kv;
      *(int4*)&Vt[row * 72 + ch * 8] = vv;
    }
    __syncthreads();

    f32x4 s[4];
#pragma unroll
    for (int j = 0; j < 4; ++j) s[j] = (f32x4){0.f, 0.f, 0.f, 0.f};
#pragma unroll
    for (int j = 0; j < 4; ++j)
#pragma unroll
      for (int f = 0; f < 2; ++f) {
        bf16x8 bk = *(const bf16x8*)&Kt[(j * 16 + lr) * 72 + f * 32 + g * 8];
        s[j] =
            __builtin_amdgcn_mfma_f32_16x16x32_bf16(aQ[f], bk, s[j], 0, 0, 0);
      }
#pragma unroll
    for (int j = 0; j < 4; ++j) {
      int kcol = k0 + j * 16 + lr;
#pragma unroll
      for (int r = 0; r < 4; ++r) {
        float sv = s[j][r] * 0.125f;
        if (kt == qt && kcol > qw + g * 4 + r) sv = -1e30f;
        s[j][r] = sv;
      }
    }
    f32x4 fr;
#pragma unroll
    for (int r = 0; r < 4; ++r) {
      float v = fmaxf(fmaxf(s[0][r], s[1][r]), fmaxf(s[2][r], s[3][r]));
#pragma unroll
      for (int d = 1; d < 16; d <<= 1) v = fmaxf(v, __shfl_xor(v, d));
      float mn = fmaxf(m4[r], v);
      fr[r] = __expf(m4[r] - mn);
      m4[r] = mn;
    }
#pragma unroll
    for (int j = 0; j < 4; ++j)
#pragma unroll
      for (int r = 0; r < 4; ++r) o[j][r] *= fr[r];
    f32x4 ps = (f32x4){0.f, 0.f, 0.f, 0.f};
#pragma unroll
    for (int j = 0; j < 4; ++j)
#pragma unroll
      for (int r = 0; r < 4; ++r) {
        float p = __expf(s[j][r] - m4[r]);
        s[j][r] = p;
        ps[r] += p;
      }
#pragma unroll
    for (int r = 0; r < 4; ++r) {
      float v = ps[r];
#pragma unroll
      for (int d = 1; d < 16; d <<= 1) v += __shfl_xor(v, d);
      l4[r] = l4[r] * fr[r] + v;
    }
#pragma unroll
    for (int j = 0; j < 4; ++j)
#pragma unroll
      for (int r = 0; r < 4; ++r)
        Pw[(g * 4 + r) * 72 + j * 16 + lr] = f2b(s[j][r]);
#pragma unroll
    for (int f = 0; f < 2; ++f) {
      bf16x8 ap = *(const bf16x8*)&Pw[lr * 72 + f * 32 + g * 8];
#pragma unroll
      for (int j = 0; j < 4; ++j) {
        bf16x8 bv = *(const bf16x8*)&Vt[(j * 16 + lr) * 72 + f * 32 + g * 8];
        o[j] = __builtin_amdgcn_mfma_f32_16x16x32_bf16(ap, bv, o[j], 0, 0, 0);
      }
    }
    __syncthreads();
  }

#pragma unroll
  for (int r = 0; r < 4; ++r) {
    float inv = 1.f / l4[r];
#pragma unroll
    for (int j = 0; j < 4; ++j)
      cx[(size_t)(b * SQ + qw + g * 4 + r) * DM + hh * DHD + j * 16 + lr] =
          f2b(o[j][r] * inv);
  }
}

// ---- merged: weight transpose (blocks 0..3071) + ln1 (blocks 3072..5119) ---
__global__ __launch_bounds__(256) void transpln_k(
    const float* __restrict__ Wq, const float* __restrict__ Wk,
    const float* __restrict__ Wv, const float* __restrict__ Wo,
    const float* __restrict__ W1, const float* __restrict__ W2,
    u16* __restrict__ wb, const float* __restrict__ x,
    const float* __restrict__ sc, const float* __restrict__ sh,
    u16* __restrict__ o) {
  __shared__ u16 tl[64][72];
  __shared__ float red[8];
  int t = threadIdx.x;
  if (blockIdx.x < 3072) {
    int id = blockIdx.x;
    const float* src;
    u16* dst;
    int K, N, ktile, ntile;
    if (id < 1024) {
      int mat = id >> 8, rem = id & 255;
      ntile = rem & 15; ktile = rem >> 4;
      src = mat == 0 ? Wq : mat == 1 ? Wk : mat == 2 ? Wv : Wo;
      dst = wb + (size_t)mat * DM * DM;
      K = DM; N = DM;
    } else if (id < 2048) {
      int rem = id - 1024;
      ntile = rem & 63; ktile = rem >> 6;
      src = W1; dst = wb + (size_t)4 * DM * DM;
      K = DM; N = DF;
    } else {
      int rem = id - 2048;
      ntile = rem & 15; ktile = rem >> 4;
      src = W2; dst = wb + (size_t)4 * DM * DM + (size_t)DM * DF;
      K = DF; N = DM;
    }
    int n0 = ntile * 64, k0 = ktile * 64;
    int tn = (t & 15) * 4, tk = t >> 4;
#pragma unroll
    for (int it = 0; it < 4; ++it) {
      int k = tk + it * 16;
      float4 v = *(const float4*)(src + (size_t)(k0 + k) * N + n0 + tn);
      tl[tn + 0][k] = f2b(v.x);
      tl[tn + 1][k] = f2b(v.y);
      tl[tn + 2][k] = f2b(v.z);
      tl[tn + 3][k] = f2b(v.w);
    }
    __syncthreads();
    int wn = t >> 3, wk = (t & 7) * 8;
#pragma unroll
    for (int it = 0; it < 2; ++it) {
      int n = wn + it * 32;
      int4 v = *(const int4*)&tl[n][wk];
      *(int4*)(dst + (size_t)(n0 + n) * K + k0 + wk) = v;
    }
  } else {
    int row = blockIdx.x - 3072;
    const float* xr = x + (size_t)row * DM;
    float4 v = *(const float4*)(xr + t * 4);
    float s = v.x + v.y + v.z + v.w;
#pragma unroll
    for (int d = 32; d; d >>= 1) s += __shfl_xor(s, d);
    if ((t & 63) == 0) red[t >> 6] = s;
    __syncthreads();
    float mean = (red[0] + red[1] + red[2] + red[3]) * (1.f / DM);
    float dx = v.x - mean, dy = v.y - mean, dz = v.z - mean, dw = v.w - mean;
    float s2 = dx * dx + dy * dy + dz * dz + dw * dw;
#pragma unroll
    for (int d = 32; d; d >>= 1) s2 += __shfl_xor(s2, d);
    if ((t & 63) == 0) red[4 + (t >> 6)] = s2;
    __syncthreads();
    float var = (red[4] + red[5] + red[6] + red[7]) * (1.f / DM);
    float rstd = 1.f / sqrtf(var + 1e-6f);
    float4 gg = *(const float4*)(sc + t * 4);
    float4 b = *(const float4*)(sh + t * 4);
    ushort4 w4;
    w4.x = f2b(gg.x * (dx * rstd) + b.x);
    w4.y = f2b(gg.y * (dy * rstd) + b.y);
    w4.z = f2b(gg.z * (dz * rstd) + b.z);
    w4.w = f2b(gg.w * (dw * rstd) + b.w);
    *(ushort4*)(o + (size_t)row * DM + t * 4) = w4;
  }
}

__global__ __launch_bounds__(256) void ln_k(const float* __restrict__ x,
                                            const float* __restrict__ sc,
                                            const float* __restrict__ sh,
                                            u16* __restrict__ o) {
  int row = blockIdx.x, t = threadIdx.x;
  const float* xr = x + (size_t)row * DM;
  float4 v = *(const float4*)(xr + t * 4);
  float s = v.x + v.y + v.z + v.w;
#pragma unroll
  for (int d = 32; d; d >>= 1) s += __shfl_xor(s, d);
  __shared__ float red[8];
  if ((t & 63) == 0) red[t >> 6] = s;
  __syncthreads();
  float mean = (red[0] + red[1] + red[2] + red[3]) * (1.f / DM);
  float dx = v.x - mean, dy = v.y - mean, dz = v.z - mean, dw = v.w - mean;
  float s2 = dx * dx + dy * dy + dz * dz + dw * dw;
#pragma unroll
  for (int d = 32; d; d >>= 1) s2 += __shfl_xor(s2, d);
  if ((t & 63) == 0) red[4 + (t >> 6)] = s2;
  __syncthreads();
  float var = (red[4] + red[5] + red[6] + red[7]) * (1.f / DM);
  float rstd = 1.f / sqrtf(var + 1e-6f);
  float4 g = *(const float4*)(sc + t * 4);
  float4 b = *(const float4*)(sh + t * 4);
  ushort4 w4;
  w4.x = f2b(g.x * (dx * rstd) + b.x);
  w4.y = f2b(g.y * (dy * rstd) + b.y);
  w4.z = f2b(g.z * (dz * rstd) + b.z);
  w4.w = f2b(g.w * (dw * rstd) + b.w);
  *(ushort4*)(o + (size_t)row * DM + t * 4) = w4;
}

// merged: embed (blocks 0..MR-1) + tok_emb bf16 conversion (rest)
__global__ __launch_bounds__(256) void embtok_k(const int* __restrict__ idx,
                                                const float* __restrict__ tok,
                                                const float* __restrict__ pos,
                                                float* __restrict__ x,
                                                u16* __restrict__ tokT) {
  int t = threadIdx.x;
  if (blockIdx.x < MR) {
    int row = blockIdx.x;
    int s = row & (SQ - 1);
    int id = idx[row];
    float4 a = *(const float4*)(tok + (size_t)id * DM + t * 4);
    float4 p = *(const float4*)(pos + (size_t)s * DM + t * 4);
    a.x += p.x; a.y += p.y; a.z += p.z; a.w += p.w;
    *(float4*)(x + (size_t)row * DM + t * 4) = a;
  } else {
    size_t r = blockIdx.x - MR;
    ushort4 w = {0, 0, 0, 0};
    if (r < NV) {
      float4 v = *(const float4*)(tok + r * DM + t * 4);
      w.x = f2b(v.x); w.y = f2b(v.y); w.z = f2b(v.z); w.w = f2b(v.w);
    }
    *(ushort4*)(tokT + r * DM + t * 4) = w;
  }
}

extern "C" void kernel_launch(void* const* d_in, const int* in_sizes, int n_in,
                              void* d_out, int out_size, void* d_ws,
                              size_t ws_size, hipStream_t stream) {
  const int* idx = (const int*)d_in[0];
  const float* tok = (const float*)d_in[1];
  const float* pos = (const float*)d_in[2];
  const float* Wq = (const float*)d_in[3];
  const float* Wk = (const float*)d_in[4];
  const float* Wv = (const float*)d_in[5];
  const float* Wo = (const float*)d_in[6];
  const float* bo = (const float*)d_in[7];
  const float* W1 = (const float*)d_in[8];
  const float* b1 = (const float*)d_in[9];
  const float* W2 = (const float*)d_in[10];
  const float* b2 = (const float*)d_in[11];
  const float* ln1s = (const float*)d_in[12];
  const float* ln1b = (const float*)d_in[13];
  const float* ln2s = (const float*)d_in[14];
  const float* ln2b = (const float*)d_in[15];
  const float* lnfs = (const float*)d_in[16];
  const float* lnfb = (const float*)d_in[17];
  float* out = (float*)d_out;

  char* w = (char*)d_ws;
  float* x = (float*)w;  w += (size_t)MR * DM * 4;
  u16* h = (u16*)w;      w += (size_t)MR * DM * 2;
  u16* qb = (u16*)w;     w += (size_t)MR * DM * 2;
  u16* kb = (u16*)w;     w += (size_t)MR * DM * 2;
  u16* vt = (u16*)w;     w += (size_t)NB * DM * SQ * 2;
  u16* ff = (u16*)w;     w += (size_t)MR * DF * 2;
  u16* wb = (u16*)w;     w += ((size_t)4 * DM * DM + 2 * (size_t)DM * DF) * 2;
  u16* tokT = (u16*)w;
  u16* cx = h;
  u16* wo_b = wb + (size_t)3 * DM * DM;
  u16* wb1 = wb + (size_t)4 * DM * DM;
  u16* wb2 = wb1 + (size_t)DM * DF;

  dim3 T(256);
  embtok_k<<<MR + NVP, T, 0, stream>>>(idx, tok, pos, x, tokT);
  for (int l = 0; l < LL; ++l) {
    size_t wo_ = (size_t)l * DM * DM;
    size_t w1_ = (size_t)l * DM * DF;
    transpln_k<<<5120, T, 0, stream>>>(Wq + wo_, Wk + wo_, Wv + wo_, Wo + wo_,
                                       W1 + w1_, W2 + w1_, wb, x, ln1s + l * DM,
                                       ln1b + l * DM, h);
    gemm_k<7, 64, 128, 5><<<768, T, 0, stream>>>(
        h, wb, qb, kb, vt, nullptr, 3 * DM, DM, DM, DM, DM);
    fattn_k<<<512, T, 0, stream>>>(qb, kb, vt, cx);
    gemm_k<1, 64, 64, 5><<<512, T, 0, stream>>>(
        cx, wo_b, x, nullptr, nullptr, bo + l * DM, DM, DM, DM, DM, DM);
    ln_k<<<MR, T, 0, stream>>>(x, ln2s + l * DM, ln2b + l * DM, h);
    gemm_k<2, 128, 128, 4><<<512, T, 0, stream>>>(
        h, wb1, ff, nullptr, nullptr, b1 + l * DF, DF, DM, DM, DM, DF);
    gemm_k<1, 64, 64, 5><<<512, T, 0, stream>>>(
        ff, wb2, x, nullptr, nullptr, b2 + l * DM, DM, DF, DF, DF, DM);
  }
  ln_k<<<MR, T, 0, stream>>>(x, lnfs, lnfb, h);
  gemmL_k<<<1576, dim3(512), 0, stream>>>(h, tokT, out);
}

// Round 9
// 2226.195 us; speedup vs baseline: 1.1286x; 1.0097x over previous
//
#include <hip/hip_runtime.h>

// GPT-2 forward. Round 9 (= round 8 with NT-store type fix): layers unchanged;
// gemmL = r7 asym-depth pipeline + coalesced NON-TEMPORAL f32x4 epilogue
// (ext_vector_type — __builtin_nontemporal_store rejects HIP_vector_type).

#define LL 12
#define DM 1024
#define NH 16
#define DHD 64
#define NV 50257
#define NVP 50432  // 197*256
#define SQ 512
#define NB 4
#define DF 4096
#define MR (NB * SQ)

typedef short bf16x8 __attribute__((ext_vector_type(8)));
typedef float f32x4 __attribute__((ext_vector_type(4)));
typedef unsigned short u16;

__device__ __forceinline__ u16 f2b(float f) {  // f32 -> bf16 RNE
  unsigned u = __float_as_uint(f);
  u += 0x7fff + ((u >> 16) & 1);
  return (u16)(u >> 16);
}

__device__ __forceinline__ void gload16(const u16* g, u16* l) {
  __builtin_amdgcn_global_load_lds(
      (const __attribute__((address_space(1))) unsigned*)g,
      (__attribute__((address_space(3))) unsigned*)l, 16, 0, 0);
}

// ---------------- layer GEMM (round-4 structure, 256 thr, 2-buffer) --------
// MODE 1: Cf32 += acc + bias   MODE 2: bf16 C = gelu(acc+bias)
// MODE 7: QKV fused (route n>>10), V transposed
template <int MODE, int TBM, int TBN, int MTLOG>
__global__ __launch_bounds__(256, 2) void gemm_k(
    const u16* __restrict__ A, const u16* __restrict__ B, void* __restrict__ Cp,
    void* __restrict__ Cp2, void* __restrict__ Cp3,
    const float* __restrict__ bias, int N, int K, int lda, int ldb, int ldc) {
  int id = blockIdx.x;
  int q8 = gridDim.x >> 3;
  int swz = (id & 7) * q8 + (id >> 3);
  int mt = swz & ((1 << MTLOG) - 1), nt = swz >> MTLOG;
  int m0 = mt * TBM, n0 = nt * TBN;

  __shared__ u16 As[2][TBM * 64];
  __shared__ u16 Bs[2][TBN * 64];

  int t = threadIdx.x, lane = t & 63, wave = t >> 6;
  int wm = wave >> 1, wn = wave & 1;
  int lr = lane & 15, g = lane >> 4;
  int srow = lane >> 3;
  int sxcol = ((lane & 7) ^ (lane >> 3)) << 3;  // inverse-swizzled global col
  int rsw = (lr & 7) << 3;                      // read-side XOR (u16 units)
  constexpr int FM = TBM / 32, FN = TBN / 32;
  constexpr int CA = TBM / 32, CB = TBN / 32;

  f32x4 acc[FM][FN];
#pragma unroll
  for (int i = 0; i < FM; ++i)
#pragma unroll
    for (int j = 0; j < FN; ++j) acc[i][j] = (f32x4){0.f, 0.f, 0.f, 0.f};

  auto stage = [&](int buf, int kt) {
    int k0 = kt * 64;
#pragma unroll
    for (int v = 0; v < CA; ++v) {
      int c = v * 4 + wave;
      gload16(A + (size_t)(m0 + c * 8 + srow) * lda + k0 + sxcol,
              &As[buf][c * 512]);
    }
#pragma unroll
    for (int v = 0; v < CB; ++v) {
      int c = v * 4 + wave;
      gload16(B + (size_t)(n0 + c * 8 + srow) * ldb + k0 + sxcol,
              &Bs[buf][c * 512]);
    }
  };

  auto compute = [&](int buf) {
    bf16x8 af[FM][2], bq[FN][2];
#pragma unroll
    for (int ks = 0; ks < 2; ++ks) {
      int co = (ks * 32 + g * 8) ^ rsw;
#pragma unroll
      for (int i = 0; i < FM; ++i)
        af[i][ks] =
            *(const bf16x8*)&As[buf][(wm * (TBM / 2) + i * 16 + lr) * 64 + co];
#pragma unroll
      for (int j = 0; j < FN; ++j)
        bq[j][ks] =
            *(const bf16x8*)&Bs[buf][(wn * (TBN / 2) + j * 16 + lr) * 64 + co];
    }
#pragma unroll
    for (int ks = 0; ks < 2; ++ks)
#pragma unroll
      for (int i = 0; i < FM; ++i)
#pragma unroll
        for (int j = 0; j < FN; ++j)
          acc[i][j] = __builtin_amdgcn_mfma_f32_16x16x32_bf16(
              af[i][ks], bq[j][ks], acc[i][j], 0, 0, 0);
  };

  int nk = K >> 6;
  stage(0, 0);
  __syncthreads();
  int cur = 0;
  for (int kt = 0; kt < nk - 1; ++kt) {
    stage(cur ^ 1, kt + 1);
    compute(cur);
    __syncthreads();
    cur ^= 1;
  }
  compute(cur);

  int rb = g * 4;
#pragma unroll
  for (int i = 0; i < FM; ++i) {
#pragma unroll
    for (int j = 0; j < FN; ++j) {
      int m = m0 + wm * (TBM / 2) + i * 16 + rb;
      int n = n0 + wn * (TBN / 2) + j * 16 + lr;
      f32x4 a = acc[i][j];
      if constexpr (MODE == 1) {
        float* C = (float*)Cp;
        float bv = bias[n];
#pragma unroll
        for (int r = 0; r < 4; ++r) {
          size_t ix = (size_t)(m + r) * ldc + n;
          C[ix] += a[r] + bv;
        }
      } else if constexpr (MODE == 2) {
        u16* C = (u16*)Cp;
        float bv = bias[n];
#pragma unroll
        for (int r = 0; r < 4; ++r) {
          float u2 = a[r] + bv;
          float gl =
              0.5f * u2 *
              (1.f + tanhf(0.7978845608f * (u2 + 0.044715f * u2 * u2 * u2)));
          C[(size_t)(m + r) * ldc + n] = f2b(gl);
        }
      } else if constexpr (MODE == 7) {
        int sel = n >> 10, nn = n & 1023;
        if (sel < 2) {
          u16* C = sel == 0 ? (u16*)Cp : (u16*)Cp2;
#pragma unroll
          for (int r = 0; r < 4; ++r) C[(size_t)(m + r) * ldc + nn] = f2b(a[r]);
        } else {  // V transposed: vt[b][d][s]
          u16* C = (u16*)Cp3;
          int bb = m >> 9, s2 = m & (SQ - 1);
          ushort4 w4;
          w4.x = f2b(a[0]); w4.y = f2b(a[1]);
          w4.z = f2b(a[2]); w4.w = f2b(a[3]);
          *(ushort4*)&C[((size_t)bb * DM + nn) * SQ + s2] = w4;
        }
      }
    }
  }
}

// ------- logits GEMM: 256x256, 8 waves, asym-depth pipeline (r7) + new -------
// coalesced NT epilogue. A 2-deep, B 3-deep in one 160KB LDS block; after the
// K-loop the LDS is reused as a 256x128 f32 staging buffer (2 passes) so C is
// written as 16B/lane non-temporal f32x4 streams.
__global__ __launch_bounds__(512, 1) void gemmL_k(const u16* __restrict__ A,
                                                  const u16* __restrict__ B,
                                                  float* __restrict__ C) {
  int id = blockIdx.x;
  int q8 = gridDim.x >> 3;
  int swz = (id & 7) * q8 + (id >> 3);
  int mt = swz & 7, nt = swz >> 3;
  int m0 = mt * 256, n0 = nt * 256;

  __shared__ __align__(16) u16 SM[81920];  // 160 KB: A slots 2x32KB, B 3x32KB

  int t = threadIdx.x, lane = t & 63, wave = t >> 6;
  int wm = wave >> 2, wn = wave & 3;  // 2M x 4N; wave tile 128x64
  int lr = lane & 15, g = lane >> 4;
  int rsw = (lr & 7) << 3;

  f32x4 acc[8][4];
#pragma unroll
  for (int i = 0; i < 8; ++i)
#pragma unroll
    for (int j = 0; j < 4; ++j) acc[i][j] = (f32x4){0.f, 0.f, 0.f, 0.f};

  auto stageA = [&](int slot, int kt) {  // 4 gload16/thread
    u16* dst = SM + slot * 16384;
    int k0 = kt * 64;
#pragma unroll
    for (int v = 0; v < 4; ++v) {
      int c = v * 512 + t;
      int row = c >> 3, cc = c & 7;
      gload16(A + (size_t)(m0 + row) * DM + k0 + ((cc ^ (row & 7)) << 3),
              dst + c * 8);
    }
  };
  auto stageB = [&](int slot, int kt) {
    u16* dst = SM + 32768 + slot * 16384;
    int k0 = kt * 64;
#pragma unroll
    for (int v = 0; v < 4; ++v) {
      int c = v * 512 + t;
      int row = c >> 3, cc = c & 7;
      gload16(B + (size_t)(n0 + row) * DM + k0 + ((cc ^ (row & 7)) << 3),
              dst + c * 8);
    }
  };
  auto compute = [&](int sa, int sb) {
    const u16* Ap = SM + sa * 16384;
    const u16* Bp = SM + 32768 + sb * 16384;
#pragma unroll
    for (int ks = 0; ks < 2; ++ks) {
      int co = (ks * 32 + g * 8) ^ rsw;
      bf16x8 af[8], bq[4];
#pragma unroll
      for (int i = 0; i < 8; ++i)
        af[i] = *(const bf16x8*)&Ap[(wm * 128 + i * 16 + lr) * 64 + co];
#pragma unroll
      for (int j = 0; j < 4; ++j)
        bq[j] = *(const bf16x8*)&Bp[(wn * 64 + j * 16 + lr) * 64 + co];
      __builtin_amdgcn_s_setprio(1);
#pragma unroll
      for (int i = 0; i < 8; ++i)
#pragma unroll
        for (int j = 0; j < 4; ++j)
          acc[i][j] = __builtin_amdgcn_mfma_f32_16x16x32_bf16(
              af[i], bq[j], acc[i][j], 0, 0, 0);
      __builtin_amdgcn_s_setprio(0);
    }
  };

  // prologue: B0,A0,B1,A1,B2 (20 loads outstanding/wave)
  stageB(0, 0); stageA(0, 0); stageB(1, 1); stageA(1, 1); stageB(2, 2);
  int sb = 0;
#pragma unroll 1
  for (int kt = 0; kt < 14; ++kt) {
    asm volatile("s_waitcnt vmcnt(12)" ::: "memory");  // B(kt),A(kt) landed
    __builtin_amdgcn_s_barrier();
    __builtin_amdgcn_sched_barrier(0);
    compute(kt & 1, sb);
    __builtin_amdgcn_s_barrier();
    __builtin_amdgcn_sched_barrier(0);
    stageA(kt & 1, kt + 2);              // refill just-read A slot
    if (kt < 13) stageB(sb, kt + 3);     // refill just-read B slot
    sb = sb + 1 == 3 ? 0 : sb + 1;
  }
  // kt=14: outstanding B14,A14,B15,A15 -> wait(8) lands B14,A14
  asm volatile("s_waitcnt vmcnt(8)" ::: "memory");
  __builtin_amdgcn_s_barrier();
  __builtin_amdgcn_sched_barrier(0);
  compute(0, 2);
  __builtin_amdgcn_s_barrier();
  __builtin_amdgcn_sched_barrier(0);
  // kt=15: drain
  asm volatile("s_waitcnt vmcnt(0)" ::: "memory");
  __builtin_amdgcn_s_barrier();
  __builtin_amdgcn_sched_barrier(0);
  compute(1, 0);

  // ---- epilogue: acc -> LDS (256x128 f32) -> coalesced NT f32x4 stores ----
  float* CS = (float*)SM;
  int rb = g * 4;
#pragma unroll 1
  for (int p = 0; p < 2; ++p) {
    __syncthreads();  // LDS free: all loop reads (and prev pass reads) done
    if ((wn >> 1) == p) {
#pragma unroll
      for (int i = 0; i < 8; ++i) {
#pragma unroll
        for (int j = 0; j < 4; ++j) {
          int row = wm * 128 + i * 16 + rb;
          int col = (wn & 1) * 64 + j * 16 + lr;
          f32x4 a = acc[i][j];
#pragma unroll
          for (int r = 0; r < 4; ++r) CS[(row + r) * 128 + col] = a[r];
        }
      }
    }
    __syncthreads();
    int base = n0 + p * 128;
#pragma unroll
    for (int k = 0; k < 16; ++k) {
      int idx = t + k * 512;
      int row = idx >> 5, c4 = (idx & 31) << 2;
      int gc = base + c4;
      f32x4 v = *(const f32x4*)&CS[row * 128 + c4];
      float* dst = &C[(size_t)(m0 + row) * NV + gc];
      if (gc + 4 <= NV) {
        __builtin_nontemporal_store(v, (f32x4*)dst);
      } else if (gc < NV) {
#pragma unroll
        for (int e = 0; e < 4; ++e)
          if (gc + e < NV) __builtin_nontemporal_store(v[e], dst + e);
      }
    }
  }
}

// -------- flash attention: one block = (qt 64 q-rows, b,h); 4 waves ---------
__global__ __launch_bounds__(256) void fattn_k(const u16* __restrict__ qb,
                                               const u16* __restrict__ kb,
                                               const u16* __restrict__ vt,
                                               u16* __restrict__ cx) {
  int id = blockIdx.x;
  int qt = id >> 6, bh = id & 63;
  int b = bh >> 4, hh = bh & 15;
  int t = threadIdx.x, lane = t & 63, w = t >> 6;
  int lr = lane & 15, g = lane >> 4;

  __shared__ u16 Kt[64 * 72];
  __shared__ u16 Vt[64 * 72];
  __shared__ u16 Pl[4 * 16 * 72];

  int qw = qt * 64 + w * 16;

  bf16x8 aQ[2];
#pragma unroll
  for (int f = 0; f < 2; ++f)
    aQ[f] = *(const bf16x8*)&qb[(size_t)(b * SQ + qw + lr) * DM + hh * DHD +
                                f * 32 + g * 8];

  f32x4 o[4];
#pragma unroll
  for (int j = 0; j < 4; ++j) o[j] = (f32x4){0.f, 0.f, 0.f, 0.f};
  f32x4 m4 = (f32x4){-3e38f, -3e38f, -3e38f, -3e38f};
  f32x4 l4 = (f32x4){0.f, 0.f, 0.f, 0.f};
  u16* Pw = &Pl[w * 16 * 72];

  for (int kt = 0; kt <= qt; ++kt) {
    int k0 = kt * 64;
#pragma unroll
    for (int it = 0; it < 2; ++it) {
      int c = t + it * 256;
      int row = c >> 3, ch = c & 7;
      int4 kv = *(const int4*)&kb[(size_t)(b * SQ + k0 + row) * DM + hh * DHD +
                                  ch * 8];
      int4 vv = *(const int4*)&vt[(size_t)(b * DM + hh * DHD + row) * SQ + k0 +
                                  ch * 8];
      *(int4*)&Kt[row * 72 + ch * 8] = kv;
      *(int4*)&Vt[row * 72 + ch * 8] = vv;
    }
    __syncthreads();

    f32x4 s[4];
#pragma unroll
    for (int j = 0; j < 4; ++j) s[j] = (f32x4){0.f, 0.f, 0.f, 0.f};
#pragma unroll
    for (int j = 0; j < 4; ++j)
#pragma unroll
      for (int f = 0; f < 2; ++f) {
        bf16x8 bk = *(const bf16x8*)&Kt[(j * 16 + lr) * 72 + f * 32 + g * 8];
        s[j] =
            __builtin_amdgcn_mfma_f32_16x16x32_bf16(aQ[f], bk, s[j], 0, 0, 0);
      }
#pragma unroll
    for (int j = 0; j < 4; ++j) {
      int kcol = k0 + j * 16 + lr;
#pragma unroll
      for (int r = 0; r < 4; ++r) {
        float sv = s[j][r] * 0.125f;
        if (kt == qt && kcol > qw + g * 4 + r) sv = -1e30f;
        s[j][r] = sv;
      }
    }
    f32x4 fr;
#pragma unroll
    for (int r = 0; r < 4; ++r) {
      float v = fmaxf(fmaxf(s[0][r], s[1][r]), fmaxf(s[2][r], s[3][r]));
#pragma unroll
      for (int d = 1; d < 16; d <<= 1) v = fmaxf(v, __shfl_xor(v, d));
      float mn = fmaxf(m4[r], v);
      fr[r] = __expf(m4[r] - mn);
      m4[r] = mn;
    }
#pragma unroll
    for (int j = 0; j < 4; ++j)
#pragma unroll
      for (int r = 0; r < 4; ++r) o[j][r] *= fr[r];
    f32x4 ps = (f32x4){0.f, 0.f, 0.f, 0.f};
#pragma unroll
    for (int j = 0; j < 4; ++j)
#pragma unroll
      for (int r = 0; r < 4; ++r) {
        float p = __expf(s[j][r] - m4[r]);
        s[j][r] = p;
        ps[r] += p;
      }
#pragma unroll
    for (int r = 0; r < 4; ++r) {
      float v = ps[r];
#pragma unroll
      for (int d = 1; d < 16; d <<= 1) v += __shfl_xor(v, d);
      l4[r] = l4[r] * fr[r] + v;
    }
#pragma unroll
    for (int j = 0; j < 4; ++j)
#pragma unroll
      for (int r = 0; r < 4; ++r)
        Pw[(g * 4 + r) * 72 + j * 16 + lr] = f2b(s[j][r]);
#pragma unroll
    for (int f = 0; f < 2; ++f) {
      bf16x8 ap = *(const bf16x8*)&Pw[lr * 72 + f * 32 + g * 8];
#pragma unroll
      for (int j = 0; j < 4; ++j) {
        bf16x8 bv = *(const bf16x8*)&Vt[(j * 16 + lr) * 72 + f * 32 + g * 8];
        o[j] = __builtin_amdgcn_mfma_f32_16x16x32_bf16(ap, bv, o[j], 0, 0, 0);
      }
    }
    __syncthreads();
  }

#pragma unroll
  for (int r = 0; r < 4; ++r) {
    float inv = 1.f / l4[r];
#pragma unroll
    for (int j = 0; j < 4; ++j)
      cx[(size_t)(b * SQ + qw + g * 4 + r) * DM + hh * DHD + j * 16 + lr] =
          f2b(o[j][r] * inv);
  }
}

// ---- merged: weight transpose (blocks 0..3071) + ln1 (blocks 3072..5119) ---
__global__ __launch_bounds__(256) void transpln_k(
    const float* __restrict__ Wq, const float* __restrict__ Wk,
    const float* __restrict__ Wv, const float* __restrict__ Wo,
    const float* __restrict__ W1, const float* __restrict__ W2,
    u16* __restrict__ wb, const float* __restrict__ x,
    const float* __restrict__ sc, const float* __restrict__ sh,
    u16* __restrict__ o) {
  __shared__ u16 tl[64][72];
  __shared__ float red[8];
  int t = threadIdx.x;
  if (blockIdx.x < 3072) {
    int id = blockIdx.x;
    const float* src;
    u16* dst;
    int K, N, ktile, ntile;
    if (id < 1024) {
      int mat = id >> 8, rem = id & 255;
      ntile = rem & 15; ktile = rem >> 4;
      src = mat == 0 ? Wq : mat == 1 ? Wk : mat == 2 ? Wv : Wo;
      dst = wb + (size_t)mat * DM * DM;
      K = DM; N = DM;
    } else if (id < 2048) {
      int rem = id - 1024;
      ntile = rem & 63; ktile = rem >> 6;
      src = W1; dst = wb + (size_t)4 * DM * DM;
      K = DM; N = DF;
    } else {
      int rem = id - 2048;
      ntile = rem & 15; ktile = rem >> 4;
      src = W2; dst = wb + (size_t)4 * DM * DM + (size_t)DM * DF;
      K = DF; N = DM;
    }
    int n0 = ntile * 64, k0 = ktile * 64;
    int tn = (t & 15) * 4, tk = t >> 4;
#pragma unroll
    for (int it = 0; it < 4; ++it) {
      int k = tk + it * 16;
      float4 v = *(const float4*)(src + (size_t)(k0 + k) * N + n0 + tn);
      tl[tn + 0][k] = f2b(v.x);
      tl[tn + 1][k] = f2b(v.y);
      tl[tn + 2][k] = f2b(v.z);
      tl[tn + 3][k] = f2b(v.w);
    }
    __syncthreads();
    int wn = t >> 3, wk = (t & 7) * 8;
#pragma unroll
    for (int it = 0; it < 2; ++it) {
      int n = wn + it * 32;
      int4 v = *(const int4*)&tl[n][wk];
      *(int4*)(dst + (size_t)(n0 + n) * K + k0 + wk) = v;
    }
  } else {
    int row = blockIdx.x - 3072;
    const float* xr = x + (size_t)row * DM;
    float4 v = *(const float4*)(xr + t * 4);
    float s = v.x + v.y + v.z + v.w;
#pragma unroll
    for (int d = 32; d; d >>= 1) s += __shfl_xor(s, d);
    if ((t & 63) == 0) red[t >> 6] = s;
    __syncthreads();
    float mean = (red[0] + red[1] + red[2] + red[3]) * (1.f / DM);
    float dx = v.x - mean, dy = v.y - mean, dz = v.z - mean, dw = v.w - mean;
    float s2 = dx * dx + dy * dy + dz * dz + dw * dw;
#pragma unroll
    for (int d = 32; d; d >>= 1) s2 += __shfl_xor(s2, d);
    if ((t & 63) == 0) red[4 + (t >> 6)] = s2;
    __syncthreads();
    float var = (red[4] + red[5] + red[6] + red[7]) * (1.f / DM);
    float rstd = 1.f / sqrtf(var + 1e-6f);
    float4 gg = *(const float4*)(sc + t * 4);
    float4 b = *(const float4*)(sh + t * 4);
    ushort4 w4;
    w4.x = f2b(gg.x * (dx * rstd) + b.x);
    w4.y = f2b(gg.y * (dy * rstd) + b.y);
    w4.z = f2b(gg.z * (dz * rstd) + b.z);
    w4.w = f2b(gg.w * (dw * rstd) + b.w);
    *(ushort4*)(o + (size_t)row * DM + t * 4) = w4;
  }
}

__global__ __launch_bounds__(256) void ln_k(const float* __restrict__ x,
                                            const float* __restrict__ sc,
                                            const float* __restrict__ sh,
                                            u16* __restrict__ o) {
  int row = blockIdx.x, t = threadIdx.x;
  const float* xr = x + (size_t)row * DM;
  float4 v = *(const float4*)(xr + t * 4);
  float s = v.x + v.y + v.z + v.w;
#pragma unroll
  for (int d = 32; d; d >>= 1) s += __shfl_xor(s, d);
  __shared__ float red[8];
  if ((t & 63) == 0) red[t >> 6] = s;
  __syncthreads();
  float mean = (red[0] + red[1] + red[2] + red[3]) * (1.f / DM);
  float dx = v.x - mean, dy = v.y - mean, dz = v.z - mean, dw = v.w - mean;
  float s2 = dx * dx + dy * dy + dz * dz + dw * dw;
#pragma unroll
  for (int d = 32; d; d >>= 1) s2 += __shfl_xor(s2, d);
  if ((t & 63) == 0) red[4 + (t >> 6)] = s2;
  __syncthreads();
  float var = (red[4] + red[5] + red[6] + red[7]) * (1.f / DM);
  float rstd = 1.f / sqrtf(var + 1e-6f);
  float4 g = *(const float4*)(sc + t * 4);
  float4 b = *(const float4*)(sh + t * 4);
  ushort4 w4;
  w4.x = f2b(g.x * (dx * rstd) + b.x);
  w4.y = f2b(g.y * (dy * rstd) + b.y);
  w4.z = f2b(g.z * (dz * rstd) + b.z);
  w4.w = f2b(g.w * (dw * rstd) + b.w);
  *(ushort4*)(o + (size_t)row * DM + t * 4) = w4;
}

// merged: embed (blocks 0..MR-1) + tok_emb bf16 conversion (rest)
__global__ __launch_bounds__(256) void embtok_k(const int* __restrict__ idx,
                                                const float* __restrict__ tok,
                                                const float* __restrict__ pos,
                                                float* __restrict__ x,
                                                u16* __restrict__ tokT) {
  int t = threadIdx.x;
  if (blockIdx.x < MR) {
    int row = blockIdx.x;
    int s = row & (SQ - 1);
    int id = idx[row];
    float4 a = *(const float4*)(tok + (size_t)id * DM + t * 4);
    float4 p = *(const float4*)(pos + (size_t)s * DM + t * 4);
    a.x += p.x; a.y += p.y; a.z += p.z; a.w += p.w;
    *(float4*)(x + (size_t)row * DM + t * 4) = a;
  } else {
    size_t r = blockIdx.x - MR;
    ushort4 w = {0, 0, 0, 0};
    if (r < NV) {
      float4 v = *(const float4*)(tok + r * DM + t * 4);
      w.x = f2b(v.x); w.y = f2b(v.y); w.z = f2b(v.z); w.w = f2b(v.w);
    }
    *(ushort4*)(tokT + r * DM + t * 4) = w;
  }
}

extern "C" void kernel_launch(void* const* d_in, const int* in_sizes, int n_in,
                              void* d_out, int out_size, void* d_ws,
                              size_t ws_size, hipStream_t stream) {
  const int* idx = (const int*)d_in[0];
  const float* tok = (const float*)d_in[1];
  const float* pos = (const float*)d_in[2];
  const float* Wq = (const float*)d_in[3];
  const float* Wk = (const float*)d_in[4];
  const float* Wv = (const float*)d_in[5];
  const float* Wo = (const float*)d_in[6];
  const float* bo = (const float*)d_in[7];
  const float* W1 = (const float*)d_in[8];
  const float* b1 = (const float*)d_in[9];
  const float* W2 = (const float*)d_in[10];
  const float* b2 = (const float*)d_in[11];
  const float* ln1s = (const float*)d_in[12];
  const float* ln1b = (const float*)d_in[13];
  const float* ln2s = (const float*)d_in[14];
  const float* ln2b = (const float*)d_in[15];
  const float* lnfs = (const float*)d_in[16];
  const float* lnfb = (const float*)d_in[17];
  float* out = (float*)d_out;

  char* w = (char*)d_ws;
  float* x = (float*)w;  w += (size_t)MR * DM * 4;
  u16* h = (u16*)w;      w += (size_t)MR * DM * 2;
  u16* qb = (u16*)w;     w += (size_t)MR * DM * 2;
  u16* kb = (u16*)w;     w += (size_t)MR * DM * 2;
  u16* vt = (u16*)w;     w += (size_t)NB * DM * SQ * 2;
  u16* ff = (u16*)w;     w += (size_t)MR * DF * 2;
  u16* wb = (u16*)w;     w += ((size_t)4 * DM * DM + 2 * (size_t)DM * DF) * 2;
  u16* tokT = (u16*)w;
  u16* cx = h;
  u16* wo_b = wb + (size_t)3 * DM * DM;
  u16* wb1 = wb + (size_t)4 * DM * DM;
  u16* wb2 = wb1 + (size_t)DM * DF;

  dim3 T(256);
  embtok_k<<<MR + NVP, T, 0, stream>>>(idx, tok, pos, x, tokT);
  for (int l = 0; l < LL; ++l) {
    size_t wo_ = (size_t)l * DM * DM;
    size_t w1_ = (size_t)l * DM * DF;
    transpln_k<<<5120, T, 0, stream>>>(Wq + wo_, Wk + wo_, Wv + wo_, Wo + wo_,
                                       W1 + w1_, W2 + w1_, wb, x, ln1s + l * DM,
                                       ln1b + l * DM, h);
    gemm_k<7, 64, 128, 5><<<768, T, 0, stream>>>(
        h, wb, qb, kb, vt, nullptr, 3 * DM, DM, DM, DM, DM);
    fattn_k<<<512, T, 0, stream>>>(qb, kb, vt, cx);
    gemm_k<1, 64, 64, 5><<<512, T, 0, stream>>>(
        cx, wo_b, x, nullptr, nullptr, bo + l * DM, DM, DM, DM, DM, DM);
    ln_k<<<MR, T, 0, stream>>>(x, ln2s + l * DM, ln2b + l * DM, h);
    gemm_k<2, 128, 128, 4><<<512, T, 0, stream>>>(
        h, wb1, ff, nullptr, nullptr, b1 + l * DF, DF, DM, DM, DM, DF);
    gemm_k<1, 64, 64, 5><<<512, T, 0, stream>>>(
        ff, wb2, x, nullptr, nullptr, b2 + l * DM, DM, DF, DF, DF, DM);
  }
  ln_k<<<MR, T, 0, stream>>>(x, lnfs, lnfb, h);
  gemmL_k<<<1576, dim3(512), 0, stream>>>(h, tokT, out);
}